// Round 3
// baseline (8391.216 us; speedup 1.0000x reference)
//
#include <hip/hip_runtime.h>
#include <stdint.h>

#define T_STEPS 64
#define BATCH   512
#define OBS_DIM 256
#define ACT_DIM 32
#define HID     1024
#define FEAT    512
#define GDIM    3072
#define KIH     288
#define NBLK    256
#define LOG2PI  1.8378770664093453f

typedef __attribute__((ext_vector_type(8))) short  short8;   // 8 bf16
typedef __attribute__((ext_vector_type(4))) float  floatx4;  // MFMA C/D frag

__device__ __forceinline__ float bf2f(unsigned short u) {
    return __uint_as_float(((unsigned int)u) << 16);
}
__device__ __forceinline__ unsigned short f2bf(float f) {
    unsigned int u = __float_as_uint(f);
    unsigned int r = (u + 0x7FFFu + ((u >> 16) & 1u)) >> 16;  // RNE
    return (unsigned short)r;
}
__device__ __forceinline__ float elu1(float x)  { return x > 0.f ? x : expm1f(x); }
__device__ __forceinline__ float sigm(float x)  { return 1.f / (1.f + expf(-x)); }

struct Params {
    const float* obs; const float* action; const float* reward;
    const float* b_ih; const float* b_hh;
    const float* b1o; const float* b1r; const float* b2o; const float* b2r;
    const unsigned short* Ws1; const unsigned short* Wih;
    const unsigned short* W1o; const unsigned short* W1r;
    const unsigned short* W2o; const unsigned short* w2r;
    const float* bias_s1;
    unsigned short* Z1; unsigned short* Z2; unsigned short* Xbuf; unsigned short* hbf;
    float* GH; float* h; float* accum; float* out;
    int* bar;
};

// ---------------------------------------------------------------------------
// Grid barrier: arrive/wait, agent (device) scope. All 256 blocks are
// co-resident by construction (33 KB LDS -> 4 blocks/CU capacity, 256 blocks
// on 256 CUs, persistent so none retires). Spin uses relaxed atomic loads;
// acquire fence on exit publishes prior stages' stores.
// ---------------------------------------------------------------------------
__device__ __forceinline__ void gbar(int* bar) {
    __syncthreads();
    if (threadIdx.x == 0) {
        int* cnt = bar;
        int* gen = bar + 32;
        int g = __hip_atomic_load(gen, __ATOMIC_RELAXED, __HIP_MEMORY_SCOPE_AGENT);
        __builtin_amdgcn_fence(__ATOMIC_RELEASE, "agent");
        int prev = __hip_atomic_fetch_add(cnt, 1, __ATOMIC_RELAXED, __HIP_MEMORY_SCOPE_AGENT);
        if (prev == NBLK - 1) {
            __hip_atomic_store(cnt, 0, __ATOMIC_RELAXED, __HIP_MEMORY_SCOPE_AGENT);
            __hip_atomic_store(gen, g + 1, __ATOMIC_RELEASE, __HIP_MEMORY_SCOPE_AGENT);
        } else {
            while (__hip_atomic_load(gen, __ATOMIC_RELAXED, __HIP_MEMORY_SCOPE_AGENT) == g)
                __builtin_amdgcn_s_sleep(1);
        }
        __builtin_amdgcn_fence(__ATOMIC_ACQUIRE, "agent");
    }
    __syncthreads();
}

// ---------------------------------------------------------------------------
// S1: C[512 x 4096] = hbf @ Ws1^T + bias; cols<1024 -> elu -> Z1; else GH.
// 256 blocks: 8 row-tiles(64) x 32 col-tiles(128). BK=64, reg-prefetch dbuf.
// ---------------------------------------------------------------------------
__device__ __forceinline__ void s1_stage(const Params& p, unsigned short* lds) {
    const int tid = threadIdx.x, lane = tid & 63, wv = tid >> 6;
    const int wr = wv & 1, wc = wv >> 1, fr = lane & 15, fq = lane >> 4;
    const int bid = blockIdx.x;
    const int row0 = (bid >> 5) * 64, col0 = (bid & 31) * 128;
    unsigned short* ldsA = lds;             // 64 x 72
    unsigned short* ldsB = lds + 64 * 72;   // 128 x 72

    floatx4 acc[2][4];
    floatx4 z4 = {0.f, 0.f, 0.f, 0.f};
#pragma unroll
    for (int m = 0; m < 2; ++m)
#pragma unroll
        for (int n = 0; n < 4; ++n) acc[m][n] = z4;

    const unsigned short* Ag = p.hbf + (size_t)row0 * HID;
    const unsigned short* Bg = p.Ws1 + (size_t)col0 * HID;
    uint4 ra[2], rb[4];
#pragma unroll
    for (int i = 0; i < 2; ++i) { int c = tid + 256 * i;
        ra[i] = *(const uint4*)(Ag + (size_t)(c >> 3) * HID + ((c & 7) << 3)); }
#pragma unroll
    for (int i = 0; i < 4; ++i) { int c = tid + 256 * i;
        rb[i] = *(const uint4*)(Bg + (size_t)(c >> 3) * HID + ((c & 7) << 3)); }

    for (int k0 = 0; k0 < 1024; k0 += 64) {
        __syncthreads();
#pragma unroll
        for (int i = 0; i < 2; ++i) { int c = tid + 256 * i;
            *(uint4*)(ldsA + (c >> 3) * 72 + ((c & 7) << 3)) = ra[i]; }
#pragma unroll
        for (int i = 0; i < 4; ++i) { int c = tid + 256 * i;
            *(uint4*)(ldsB + (c >> 3) * 72 + ((c & 7) << 3)) = rb[i]; }
        __syncthreads();
        if (k0 + 64 < 1024) {
#pragma unroll
            for (int i = 0; i < 2; ++i) { int c = tid + 256 * i;
                ra[i] = *(const uint4*)(Ag + (size_t)(c >> 3) * HID + k0 + 64 + ((c & 7) << 3)); }
#pragma unroll
            for (int i = 0; i < 4; ++i) { int c = tid + 256 * i;
                rb[i] = *(const uint4*)(Bg + (size_t)(c >> 3) * HID + k0 + 64 + ((c & 7) << 3)); }
        }
#pragma unroll
        for (int ks = 0; ks < 2; ++ks) {
            short8 af[2], bf8[4];
#pragma unroll
            for (int m = 0; m < 2; ++m)
                af[m] = *(const short8*)(ldsA + (wr * 32 + m * 16 + fr) * 72 + ks * 32 + fq * 8);
#pragma unroll
            for (int n = 0; n < 4; ++n)
                bf8[n] = *(const short8*)(ldsB + (wc * 64 + n * 16 + fr) * 72 + ks * 32 + fq * 8);
#pragma unroll
            for (int m = 0; m < 2; ++m)
#pragma unroll
                for (int n = 0; n < 4; ++n)
                    acc[m][n] = __builtin_amdgcn_mfma_f32_16x16x32_bf16(
                        af[m], bf8[n], acc[m][n], 0, 0, 0);
        }
    }
#pragma unroll
    for (int m = 0; m < 2; ++m)
#pragma unroll
        for (int n = 0; n < 4; ++n)
#pragma unroll
            for (int j = 0; j < 4; ++j) {
                int row = row0 + wr * 32 + m * 16 + fq * 4 + j;
                int col = col0 + wc * 64 + n * 16 + fr;
                float v = acc[m][n][j] + p.bias_s1[col];
                if (col < 1024) p.Z1[row * HID + col] = f2bf(elu1(v));
                else            p.GH[(size_t)row * GDIM + col - 1024] = v;
            }
}

// ---------------------------------------------------------------------------
// S2: Z2[:, z*512+col] = elu(Z1[:, z*512:] @ W1z^T + b1z).
// 256 blocks: 16 row-tiles(32) x (2 z x 8 col-tiles(64)). K=512, BK=64.
// ---------------------------------------------------------------------------
__device__ __forceinline__ void s2_stage(const Params& p, unsigned short* lds) {
    const int tid = threadIdx.x, lane = tid & 63, wv = tid >> 6;
    const int wr = wv & 1, wc = wv >> 1, fr = lane & 15, fq = lane >> 4;
    const int bid = blockIdx.x;
    const int row0 = (bid >> 4) * 32;
    const int ct = bid & 15, z = ct >> 3, col0 = (ct & 7) * 64;
    unsigned short* ldsA = lds;             // 32 x 72
    unsigned short* ldsB = lds + 32 * 72;   // 64 x 72

    floatx4 acc[2];
    floatx4 z4 = {0.f, 0.f, 0.f, 0.f};
    acc[0] = z4; acc[1] = z4;

    const unsigned short* Ag = p.Z1 + (size_t)row0 * HID + z * FEAT;
    const unsigned short* Bg = (z ? p.W1r : p.W1o) + (size_t)col0 * FEAT;
    const float* bias = z ? p.b1r : p.b1o;

    uint4 ra, rb[2];
    ra = *(const uint4*)(Ag + (size_t)(tid >> 3) * HID + ((tid & 7) << 3));
#pragma unroll
    for (int i = 0; i < 2; ++i) { int c = tid + 256 * i;
        rb[i] = *(const uint4*)(Bg + (size_t)(c >> 3) * FEAT + ((c & 7) << 3)); }

    for (int k0 = 0; k0 < 512; k0 += 64) {
        __syncthreads();
        *(uint4*)(ldsA + (tid >> 3) * 72 + ((tid & 7) << 3)) = ra;
#pragma unroll
        for (int i = 0; i < 2; ++i) { int c = tid + 256 * i;
            *(uint4*)(ldsB + (c >> 3) * 72 + ((c & 7) << 3)) = rb[i]; }
        __syncthreads();
        if (k0 + 64 < 512) {
            ra = *(const uint4*)(Ag + (size_t)(tid >> 3) * HID + k0 + 64 + ((tid & 7) << 3));
#pragma unroll
            for (int i = 0; i < 2; ++i) { int c = tid + 256 * i;
                rb[i] = *(const uint4*)(Bg + (size_t)(c >> 3) * FEAT + k0 + 64 + ((c & 7) << 3)); }
        }
#pragma unroll
        for (int ks = 0; ks < 2; ++ks) {
            short8 af = *(const short8*)(ldsA + (wr * 16 + fr) * 72 + ks * 32 + fq * 8);
#pragma unroll
            for (int n = 0; n < 2; ++n) {
                short8 bf8 = *(const short8*)(ldsB + (wc * 32 + n * 16 + fr) * 72 + ks * 32 + fq * 8);
                acc[n] = __builtin_amdgcn_mfma_f32_16x16x32_bf16(af, bf8, acc[n], 0, 0, 0);
            }
        }
    }
#pragma unroll
    for (int n = 0; n < 2; ++n)
#pragma unroll
        for (int j = 0; j < 4; ++j) {
            int row = row0 + wr * 16 + fq * 4 + j;
            int col = col0 + wc * 32 + n * 16 + fr;
            float v = acc[n][j] + bias[col];
            p.Z2[row * HID + z * FEAT + col] = f2bf(elu1(v));
        }
}

// ---------------------------------------------------------------------------
// S3: bids 0..127: obs head 32x32 tiles (16x8) -> out, Xbuf, sq-loss.
//     bids 128..135: reward head (64 rows each). bids 136..143: act copy.
// ---------------------------------------------------------------------------
__device__ __forceinline__ void s3_stage(const Params& p, unsigned short* lds, int t) {
    const int tid = threadIdx.x, lane = tid & 63, wv = tid >> 6;
    const int wr = wv & 1, wc = wv >> 1, fr = lane & 15, fq = lane >> 4;
    const int bid = blockIdx.x;

    if (bid < 128) {
        const int row0 = (bid >> 3) * 32, col0 = (bid & 7) * 32;
        unsigned short* ldsA = lds;             // 32 x 72
        unsigned short* ldsB = lds + 32 * 72;   // 32 x 72
        floatx4 acc = {0.f, 0.f, 0.f, 0.f};

        const unsigned short* Ag = p.Z2 + (size_t)row0 * HID;   // obs half: cols 0..511
        const unsigned short* Bg = p.W2o + (size_t)col0 * FEAT;
        uint4 ra, rb;
        ra = *(const uint4*)(Ag + (size_t)(tid >> 3) * HID + ((tid & 7) << 3));
        rb = *(const uint4*)(Bg + (size_t)(tid >> 3) * FEAT + ((tid & 7) << 3));
        for (int k0 = 0; k0 < 512; k0 += 64) {
            __syncthreads();
            *(uint4*)(ldsA + (tid >> 3) * 72 + ((tid & 7) << 3)) = ra;
            *(uint4*)(ldsB + (tid >> 3) * 72 + ((tid & 7) << 3)) = rb;
            __syncthreads();
            if (k0 + 64 < 512) {
                ra = *(const uint4*)(Ag + (size_t)(tid >> 3) * HID + k0 + 64 + ((tid & 7) << 3));
                rb = *(const uint4*)(Bg + (size_t)(tid >> 3) * FEAT + k0 + 64 + ((tid & 7) << 3));
            }
#pragma unroll
            for (int ks = 0; ks < 2; ++ks) {
                short8 af = *(const short8*)(ldsA + (wr * 16 + fr) * 72 + ks * 32 + fq * 8);
                short8 bf8 = *(const short8*)(ldsB + (wc * 16 + fr) * 72 + ks * 32 + fq * 8);
                acc = __builtin_amdgcn_mfma_f32_16x16x32_bf16(af, bf8, acc, 0, 0, 0);
            }
        }
        float lsum = 0.f;
#pragma unroll
        for (int j = 0; j < 4; ++j) {
            int row = row0 + wr * 16 + fq * 4 + j;
            int col = col0 + wc * 16 + fr;
            float mval = acc[j] + p.b2o[col];
            size_t oidx = (size_t)t * BATCH * OBS_DIM + (size_t)row * OBS_DIM + col;
            p.out[1 + oidx] = mval;
            p.Xbuf[row * KIH + col] = f2bf(mval);
            float d = p.obs[oidx] - mval;
            lsum += d * d;
        }
#pragma unroll
        for (int off = 32; off > 0; off >>= 1) lsum += __shfl_down(lsum, off, 64);
        if (lane == 0) atomicAdd(p.accum + 0, lsum);
    } else if (bid < 136) {
        // reward head: 64 rows, 4 waves x 16 rows
        const int r0 = (bid - 128) * 64;
        short8 wv8 = *(const short8*)(p.w2r + lane * 8);
        float wsum = 0.f;
        for (int i = 0; i < 16; ++i) {
            int row = r0 + wv * 16 + i;
            short8 zv = *(const short8*)(p.Z2 + (size_t)row * HID + FEAT + lane * 8);
            float s = 0.f;
#pragma unroll
            for (int j = 0; j < 8; ++j)
                s += bf2f((unsigned short)zv[j]) * bf2f((unsigned short)wv8[j]);
#pragma unroll
            for (int off = 32; off > 0; off >>= 1) s += __shfl_down(s, off, 64);
            if (lane == 0) {
                float m = s + p.b2r[0];
                p.out[1 + (size_t)T_STEPS * BATCH * OBS_DIM + (size_t)t * BATCH + row] = m;
                float d = p.reward[(size_t)t * BATCH + row] - m;
                wsum += d * d;
            }
        }
        if (lane == 0) atomicAdd(p.accum + 1, wsum);
    } else if (bid < 144) {
        const int r0 = (bid - 136) * 64;
        for (int e = tid; e < 64 * ACT_DIM; e += 256) {
            int row = r0 + (e >> 5), col = e & 31;
            p.Xbuf[row * KIH + OBS_DIM + col] =
                f2bf(p.action[((size_t)t * BATCH + row) * ACT_DIM + col]);
        }
    }
}

// ---------------------------------------------------------------------------
// S4: gi = Xbuf[512 x 288] @ Wih^T (3 gates), fused GRU gates -> h, hbf.
// 256 blocks: 8 row-tiles(64) x 32 col-tiles(32 hid-cols, all 3 gates).
// K=288, BK=96 (3 iters).
// ---------------------------------------------------------------------------
__device__ __forceinline__ void s4_stage(const Params& p, unsigned short* lds, int use_gh) {
    const int tid = threadIdx.x, lane = tid & 63, wv = tid >> 6;
    const int wr = wv & 1, wc = wv >> 1, fr = lane & 15, fq = lane >> 4;
    const int bid = blockIdx.x;
    const int row0 = (bid >> 5) * 64, col0 = (bid & 31) * 32;
    unsigned short* ldsA = lds;              // 64 x 104
    unsigned short* ldsB = lds + 64 * 104;   // 96 x 104

    floatx4 acc[3][2];
    floatx4 z4 = {0.f, 0.f, 0.f, 0.f};
#pragma unroll
    for (int g = 0; g < 3; ++g) { acc[g][0] = z4; acc[g][1] = z4; }

    for (int k0 = 0; k0 < KIH; k0 += 96) {
        __syncthreads();
        for (int c = tid; c < 768; c += 256) {
            int r = c / 12, ko = (c - r * 12) * 8;
            *(uint4*)(ldsA + r * 104 + ko) =
                *(const uint4*)(p.Xbuf + (size_t)(row0 + r) * KIH + k0 + ko);
        }
        for (int c = tid; c < 1152; c += 256) {
            int r = c / 12, ko = (c - r * 12) * 8;
            int g = r >> 5, cr = r & 31;
            *(uint4*)(ldsB + r * 104 + ko) =
                *(const uint4*)(p.Wih + (size_t)(g * HID + col0 + cr) * KIH + k0 + ko);
        }
        __syncthreads();
#pragma unroll
        for (int ks = 0; ks < 3; ++ks) {
            short8 af[2];
#pragma unroll
            for (int m = 0; m < 2; ++m)
                af[m] = *(const short8*)(ldsA + (wr * 32 + m * 16 + fr) * 104 + ks * 32 + fq * 8);
#pragma unroll
            for (int g = 0; g < 3; ++g) {
                short8 bf8 = *(const short8*)(ldsB + (g * 32 + wc * 16 + fr) * 104 + ks * 32 + fq * 8);
#pragma unroll
                for (int m = 0; m < 2; ++m)
                    acc[g][m] = __builtin_amdgcn_mfma_f32_16x16x32_bf16(
                        af[m], bf8, acc[g][m], 0, 0, 0);
            }
        }
    }
#pragma unroll
    for (int m = 0; m < 2; ++m)
#pragma unroll
        for (int j = 0; j < 4; ++j) {
            int row = row0 + wr * 32 + m * 16 + fq * 4 + j;
            int col = col0 + wc * 16 + fr;
            float gr = acc[0][m][j] + p.b_ih[col];
            float gz = acc[1][m][j] + p.b_ih[HID + col];
            float gn = acc[2][m][j] + p.b_ih[2 * HID + col];
            float hr, hz, hn, hp;
            if (use_gh) {
                hr = p.GH[(size_t)row * GDIM + col];
                hz = p.GH[(size_t)row * GDIM + HID + col];
                hn = p.GH[(size_t)row * GDIM + 2 * HID + col];
                hp = p.h[(size_t)row * HID + col];
            } else {
                hr = p.b_hh[col];
                hz = p.b_hh[HID + col];
                hn = p.b_hh[2 * HID + col];
                hp = 0.f;
            }
            float r  = sigm(gr + hr);
            float z  = sigm(gz + hz);
            float nn = tanhf(gn + r * hn);
            float hv = (1.f - z) * nn + z * hp;
            p.h[(size_t)row * HID + col]   = hv;
            p.hbf[(size_t)row * HID + col] = f2bf(hv);
        }
}

// ---------------------------------------------------------------------------
// Persistent rollout kernel: plain launch; all 256 blocks co-resident
// (33 KB LDS -> 4 blocks/CU capacity, 1 needed). Grid sync via gbar.
// ---------------------------------------------------------------------------
__global__ __launch_bounds__(256, 1) void k_persist(Params p) {
    __shared__ unsigned short lds[16640];   // max stage footprint (S4: 33.3 KB)

    // h0 = GRU([obs0, 0], 0); Xbuf pre-filled by k_init
    s4_stage(p, lds, 0);
    gbar(p.bar);

    for (int t = 0; t < T_STEPS; ++t) {
        s1_stage(p, lds);
        gbar(p.bar);
        s2_stage(p, lds);
        gbar(p.bar);
        s3_stage(p, lds, t);
        gbar(p.bar);
        if (t < T_STEPS - 1) {
            s4_stage(p, lds, 1);
            gbar(p.bar);
        }
    }
    if (blockIdx.x == 0 && threadIdx.x == 0) {
        const float inv = 1.f / (float)(T_STEPS * BATCH);
        p.out[0] = 0.5f * p.accum[0] * inv + 128.f * LOG2PI
                 + 0.5f * p.accum[1] * inv + 0.5f * LOG2PI;
    }
}

// ---------------------------------------------------------------------------
__global__ void k_convert(
    const float* __restrict__ ow0, const float* __restrict__ rw0,
    const float* __restrict__ whh, const float* __restrict__ wih,
    const float* __restrict__ ow1, const float* __restrict__ rw1,
    const float* __restrict__ ow2, const float* __restrict__ rw2,
    const float* __restrict__ ob0, const float* __restrict__ rb0,
    const float* __restrict__ bhh,
    unsigned short* __restrict__ Ws1, unsigned short* __restrict__ Wih,
    unsigned short* __restrict__ W1o, unsigned short* __restrict__ W1r,
    unsigned short* __restrict__ W2o, unsigned short* __restrict__ w2r,
    float* __restrict__ bias_s1)
{
    const int i0 = blockIdx.x * 256 + threadIdx.x;
    const int stride = gridDim.x * 256;
    for (int i = i0; i < 4096 * 1024; i += stride) {
        int row = i >> 10;
        float v = (row < 512) ? ow0[i]
                : (row < 1024) ? rw0[i - 512 * 1024]
                               : whh[i - 1024 * 1024];
        Ws1[i] = f2bf(v);
    }
    for (int i = i0; i < GDIM * KIH; i += stride) Wih[i] = f2bf(wih[i]);
    for (int i = i0; i < FEAT * FEAT; i += stride) {
        W1o[i] = f2bf(ow1[i]);
        W1r[i] = f2bf(rw1[i]);
    }
    for (int i = i0; i < OBS_DIM * FEAT; i += stride) W2o[i] = f2bf(ow2[i]);
    for (int i = i0; i < FEAT; i += stride) w2r[i] = f2bf(rw2[i]);
    for (int i = i0; i < 4096; i += stride)
        bias_s1[i] = (i < 512) ? ob0[i] : (i < 1024) ? rb0[i - 512] : bhh[i - 1024];
}

__global__ void k_init(const float* __restrict__ obs,
                       unsigned short* __restrict__ Xbuf,
                       float* __restrict__ accum,
                       int* __restrict__ bar)
{
    int i = blockIdx.x * 256 + threadIdx.x;
    if (i < BATCH * KIH) {
        int row = i / KIH, col = i - row * KIH;
        Xbuf[i] = (col < OBS_DIM) ? f2bf(obs[row * OBS_DIM + col]) : (unsigned short)0;
    }
    if (i < 2)  accum[i] = 0.f;
    if (i < 64) bar[i] = 0;
}

// ---------------------------------------------------------------------------
extern "C" void kernel_launch(void* const* d_in, const int* in_sizes, int n_in,
                              void* d_out, int out_size, void* d_ws, size_t ws_size,
                              hipStream_t stream)
{
    const float* obs      = (const float*)d_in[0];
    const float* action   = (const float*)d_in[1];
    const float* reward   = (const float*)d_in[2];
    const float* gru_w_ih = (const float*)d_in[3];
    const float* gru_w_hh = (const float*)d_in[4];
    const float* gru_b_ih = (const float*)d_in[5];
    const float* gru_b_hh = (const float*)d_in[6];
    const float* obs_w0   = (const float*)d_in[7];
    const float* obs_b0   = (const float*)d_in[8];
    const float* obs_w1   = (const float*)d_in[9];
    const float* obs_b1   = (const float*)d_in[10];
    const float* obs_w2   = (const float*)d_in[11];
    const float* obs_b2   = (const float*)d_in[12];
    const float* rew_w0   = (const float*)d_in[13];
    const float* rew_b0   = (const float*)d_in[14];
    const float* rew_w1   = (const float*)d_in[15];
    const float* rew_b1   = (const float*)d_in[16];
    const float* rew_w2   = (const float*)d_in[17];
    const float* rew_b2   = (const float*)d_in[18];

    char* ws = (char*)d_ws;
    auto alloc = [&](size_t bytes) -> char* {
        char* pr = ws;
        ws += (bytes + 255) & ~(size_t)255;
        return pr;
    };
    unsigned short* Ws1     = (unsigned short*)alloc((size_t)4096 * 1024 * 2);
    unsigned short* Wih     = (unsigned short*)alloc((size_t)GDIM * KIH * 2);
    unsigned short* W1o     = (unsigned short*)alloc((size_t)FEAT * FEAT * 2);
    unsigned short* W1r     = (unsigned short*)alloc((size_t)FEAT * FEAT * 2);
    unsigned short* W2o     = (unsigned short*)alloc((size_t)OBS_DIM * FEAT * 2);
    unsigned short* w2r     = (unsigned short*)alloc((size_t)FEAT * 2);
    float*          bias_s1 = (float*)alloc((size_t)4096 * 4);
    unsigned short* Z1      = (unsigned short*)alloc((size_t)BATCH * HID * 2);
    unsigned short* Z2      = (unsigned short*)alloc((size_t)BATCH * HID * 2);
    float*          GH      = (float*)alloc((size_t)BATCH * GDIM * 4);
    unsigned short* Xbuf    = (unsigned short*)alloc((size_t)BATCH * KIH * 2);
    float*          h       = (float*)alloc((size_t)BATCH * HID * 4);
    unsigned short* hbf     = (unsigned short*)alloc((size_t)BATCH * HID * 2);
    float*          accum   = (float*)alloc(256);
    int*            bar     = (int*)alloc(256);

    dim3 blk(256);

    k_convert<<<dim3(1024), blk, 0, stream>>>(
        obs_w0, rew_w0, gru_w_hh, gru_w_ih, obs_w1, rew_w1, obs_w2, rew_w2,
        obs_b0, rew_b0, gru_b_hh, Ws1, Wih, W1o, W1r, W2o, w2r, bias_s1);

    k_init<<<dim3((BATCH * KIH + 255) / 256), blk, 0, stream>>>(obs, Xbuf, accum, bar);

    Params hp;
    hp.obs = obs; hp.action = action; hp.reward = reward;
    hp.b_ih = gru_b_ih; hp.b_hh = gru_b_hh;
    hp.b1o = obs_b1; hp.b1r = rew_b1; hp.b2o = obs_b2; hp.b2r = rew_b2;
    hp.Ws1 = Ws1; hp.Wih = Wih; hp.W1o = W1o; hp.W1r = W1r;
    hp.W2o = W2o; hp.w2r = w2r; hp.bias_s1 = bias_s1;
    hp.Z1 = Z1; hp.Z2 = Z2; hp.Xbuf = Xbuf; hp.hbf = hbf;
    hp.GH = GH; hp.h = h; hp.accum = accum; hp.out = (float*)d_out;
    hp.bar = bar;

    k_persist<<<dim3(NBLK), blk, 0, stream>>>(hp);
}

// Round 4
// 7252.459 us; speedup vs baseline: 1.1570x; 1.1570x over previous
//
#include <hip/hip_runtime.h>
#include <stdint.h>

#define T_STEPS 64
#define BATCH   512
#define OBS_DIM 256
#define ACT_DIM 32
#define HID     1024
#define FEAT    512
#define GDIM    3072
#define KIH     288
#define NBLK    256
#define LOG2PI  1.8378770664093453f

typedef __attribute__((ext_vector_type(8))) short  short8;   // 8 bf16
typedef __attribute__((ext_vector_type(4))) float  floatx4;  // MFMA C/D frag

__device__ __forceinline__ float bf2f(unsigned int u) {
    return __uint_as_float(u << 16);
}
__device__ __forceinline__ unsigned int f2bf(float f) {
    unsigned int u = __float_as_uint(f);
    return (u + 0x7FFFu + ((u >> 16) & 1u)) >> 16;  // RNE
}
__device__ __forceinline__ float elu1(float x)  { return x > 0.f ? x : expm1f(x); }
__device__ __forceinline__ float sigm(float x)  { return 1.f / (1.f + expf(-x)); }

// ---------------------------------------------------------------------------
// Device-coherent (L1/L2-bypassing) accessors for mutable inter-stage data.
// Relaxed agent-scope atomics compile to sc0/sc1-flagged global ops that are
// coherent across XCDs WITHOUT any L2 writeback/invalidate fences.
// Weights stay in plain (cached) loads -> L2-resident across all 64 steps.
// ---------------------------------------------------------------------------
__device__ __forceinline__ unsigned int dev_ld(const unsigned int* p) {
    return __hip_atomic_load(p, __ATOMIC_RELAXED, __HIP_MEMORY_SCOPE_AGENT);
}
__device__ __forceinline__ void dev_st(unsigned int* p, unsigned int v) {
    __hip_atomic_store(p, v, __ATOMIC_RELAXED, __HIP_MEMORY_SCOPE_AGENT);
}
__device__ __forceinline__ uint4 dev_ld4(const unsigned short* p) {
    const unsigned int* q = (const unsigned int*)p;
    uint4 r;
    r.x = dev_ld(q + 0); r.y = dev_ld(q + 1);
    r.z = dev_ld(q + 2); r.w = dev_ld(q + 3);
    return r;
}
__device__ __forceinline__ float dev_ldf(const float* p) {
    return __uint_as_float(dev_ld((const unsigned int*)p));
}
__device__ __forceinline__ void dev_stf(float* p, float v) {
    dev_st((unsigned int*)p, __float_as_uint(v));
}

struct Params {
    const float* obs; const float* action; const float* reward;
    const float* b_ih; const float* b_hh;
    const float* b1o; const float* b1r; const float* b2o; const float* b2r;
    const unsigned short* Ws1; const unsigned short* Wih;
    const unsigned short* W1o; const unsigned short* W1r;
    const unsigned short* W2o; const unsigned short* w2r;
    const float* bias_s1;
    unsigned short* Z1; unsigned short* Z2; unsigned short* Xbuf; unsigned short* hbf;
    float* GH; float* h; float* accum; float* out;
    int* bar;
};

// ---------------------------------------------------------------------------
// Grid barrier: relaxed agent atomics only (no cache-maintenance fences).
// Data coherence is carried by the dev_ld/dev_st accessors, not the barrier.
// Workgroup-scope fences pin compiler ordering; __syncthreads drains vmcnt.
// ---------------------------------------------------------------------------
__device__ __forceinline__ void gbar(int* bar) {
    __syncthreads();   // all waves' stores drained (vmcnt 0) before arrive
    if (threadIdx.x == 0) {
        int* cnt = bar;
        int* gen = bar + 32;
        __builtin_amdgcn_fence(__ATOMIC_RELEASE, "workgroup");
        int g = __hip_atomic_load(gen, __ATOMIC_RELAXED, __HIP_MEMORY_SCOPE_AGENT);
        int prev = __hip_atomic_fetch_add(cnt, 1, __ATOMIC_RELAXED, __HIP_MEMORY_SCOPE_AGENT);
        if (prev == NBLK - 1) {
            __hip_atomic_store(cnt, 0, __ATOMIC_RELAXED, __HIP_MEMORY_SCOPE_AGENT);
            __hip_atomic_store(gen, g + 1, __ATOMIC_RELAXED, __HIP_MEMORY_SCOPE_AGENT);
        } else {
            while (__hip_atomic_load(gen, __ATOMIC_RELAXED, __HIP_MEMORY_SCOPE_AGENT) == g)
                __builtin_amdgcn_s_sleep(2);
        }
        __builtin_amdgcn_fence(__ATOMIC_ACQUIRE, "workgroup");
    }
    __syncthreads();
}

// ---------------------------------------------------------------------------
// S1: C[512 x 4096] = hbf @ Ws1^T + bias; cols<1024 -> elu -> Z1; else GH.
// 256 blocks: 8 row-tiles(64) x 32 col-tiles(128). BK=64, reg-prefetch dbuf.
// ---------------------------------------------------------------------------
__device__ __forceinline__ void s1_stage(const Params& p, unsigned short* lds) {
    const int tid = threadIdx.x, lane = tid & 63, wv = tid >> 6;
    const int wr = wv & 1, wc = wv >> 1, fr = lane & 15, fq = lane >> 4;
    const int bid = blockIdx.x;
    const int row0 = (bid >> 5) * 64, col0 = (bid & 31) * 128;
    unsigned short* ldsA = lds;             // 64 x 72
    unsigned short* ldsB = lds + 64 * 72;   // 128 x 72

    floatx4 acc[2][4];
    floatx4 z4 = {0.f, 0.f, 0.f, 0.f};
#pragma unroll
    for (int m = 0; m < 2; ++m)
#pragma unroll
        for (int n = 0; n < 4; ++n) acc[m][n] = z4;

    const unsigned short* Ag = p.hbf + (size_t)row0 * HID;
    const unsigned short* Bg = p.Ws1 + (size_t)col0 * HID;
    uint4 ra[2], rb[4];
#pragma unroll
    for (int i = 0; i < 2; ++i) { int c = tid + 256 * i;
        ra[i] = dev_ld4(Ag + (size_t)(c >> 3) * HID + ((c & 7) << 3)); }
#pragma unroll
    for (int i = 0; i < 4; ++i) { int c = tid + 256 * i;
        rb[i] = *(const uint4*)(Bg + (size_t)(c >> 3) * HID + ((c & 7) << 3)); }

    for (int k0 = 0; k0 < 1024; k0 += 64) {
        __syncthreads();
#pragma unroll
        for (int i = 0; i < 2; ++i) { int c = tid + 256 * i;
            *(uint4*)(ldsA + (c >> 3) * 72 + ((c & 7) << 3)) = ra[i]; }
#pragma unroll
        for (int i = 0; i < 4; ++i) { int c = tid + 256 * i;
            *(uint4*)(ldsB + (c >> 3) * 72 + ((c & 7) << 3)) = rb[i]; }
        __syncthreads();
        if (k0 + 64 < 1024) {
#pragma unroll
            for (int i = 0; i < 2; ++i) { int c = tid + 256 * i;
                ra[i] = dev_ld4(Ag + (size_t)(c >> 3) * HID + k0 + 64 + ((c & 7) << 3)); }
#pragma unroll
            for (int i = 0; i < 4; ++i) { int c = tid + 256 * i;
                rb[i] = *(const uint4*)(Bg + (size_t)(c >> 3) * HID + k0 + 64 + ((c & 7) << 3)); }
        }
#pragma unroll
        for (int ks = 0; ks < 2; ++ks) {
            short8 af[2], bf8[4];
#pragma unroll
            for (int m = 0; m < 2; ++m)
                af[m] = *(const short8*)(ldsA + (wr * 32 + m * 16 + fr) * 72 + ks * 32 + fq * 8);
#pragma unroll
            for (int n = 0; n < 4; ++n)
                bf8[n] = *(const short8*)(ldsB + (wc * 64 + n * 16 + fr) * 72 + ks * 32 + fq * 8);
#pragma unroll
            for (int m = 0; m < 2; ++m)
#pragma unroll
                for (int n = 0; n < 4; ++n)
                    acc[m][n] = __builtin_amdgcn_mfma_f32_16x16x32_bf16(
                        af[m], bf8[n], acc[m][n], 0, 0, 0);
        }
    }
    const bool isZ1 = (col0 < 1024);
#pragma unroll
    for (int m = 0; m < 2; ++m)
#pragma unroll
        for (int n = 0; n < 4; ++n)
#pragma unroll
            for (int j = 0; j < 4; ++j) {
                int row = row0 + wr * 32 + m * 16 + fq * 4 + j;
                int col = col0 + wc * 64 + n * 16 + fr;
                float v = acc[m][n][j] + p.bias_s1[col];
                if (isZ1) {
                    unsigned int ow = f2bf(elu1(v));
                    unsigned int pr = __shfl_xor(ow, 1, 64);
                    if (!(fr & 1))
                        dev_st((unsigned int*)(p.Z1 + row * HID + col), ow | (pr << 16));
                } else {
                    dev_stf(p.GH + (size_t)row * GDIM + (col - 1024), v);
                }
            }
}

// ---------------------------------------------------------------------------
// S2: Z2[:, z*512+col] = elu(Z1[:, z*512:] @ W1z^T + b1z).
// 256 blocks: 16 row-tiles(32) x (2 z x 8 col-tiles(64)). K=512, BK=64.
// ---------------------------------------------------------------------------
__device__ __forceinline__ void s2_stage(const Params& p, unsigned short* lds) {
    const int tid = threadIdx.x, lane = tid & 63, wv = tid >> 6;
    const int wr = wv & 1, wc = wv >> 1, fr = lane & 15, fq = lane >> 4;
    const int bid = blockIdx.x;
    const int row0 = (bid >> 4) * 32;
    const int ct = bid & 15, z = ct >> 3, col0 = (ct & 7) * 64;
    unsigned short* ldsA = lds;             // 32 x 72
    unsigned short* ldsB = lds + 32 * 72;   // 64 x 72

    floatx4 acc[2];
    floatx4 z4 = {0.f, 0.f, 0.f, 0.f};
    acc[0] = z4; acc[1] = z4;

    const unsigned short* Ag = p.Z1 + (size_t)row0 * HID + z * FEAT;
    const unsigned short* Bg = (z ? p.W1r : p.W1o) + (size_t)col0 * FEAT;
    const float* bias = z ? p.b1r : p.b1o;

    uint4 ra, rb[2];
    ra = dev_ld4(Ag + (size_t)(tid >> 3) * HID + ((tid & 7) << 3));
#pragma unroll
    for (int i = 0; i < 2; ++i) { int c = tid + 256 * i;
        rb[i] = *(const uint4*)(Bg + (size_t)(c >> 3) * FEAT + ((c & 7) << 3)); }

    for (int k0 = 0; k0 < 512; k0 += 64) {
        __syncthreads();
        *(uint4*)(ldsA + (tid >> 3) * 72 + ((tid & 7) << 3)) = ra;
#pragma unroll
        for (int i = 0; i < 2; ++i) { int c = tid + 256 * i;
            *(uint4*)(ldsB + (c >> 3) * 72 + ((c & 7) << 3)) = rb[i]; }
        __syncthreads();
        if (k0 + 64 < 512) {
            ra = dev_ld4(Ag + (size_t)(tid >> 3) * HID + k0 + 64 + ((tid & 7) << 3));
#pragma unroll
            for (int i = 0; i < 2; ++i) { int c = tid + 256 * i;
                rb[i] = *(const uint4*)(Bg + (size_t)(c >> 3) * FEAT + k0 + 64 + ((c & 7) << 3)); }
        }
#pragma unroll
        for (int ks = 0; ks < 2; ++ks) {
            short8 af = *(const short8*)(ldsA + (wr * 16 + fr) * 72 + ks * 32 + fq * 8);
#pragma unroll
            for (int n = 0; n < 2; ++n) {
                short8 bf8 = *(const short8*)(ldsB + (wc * 32 + n * 16 + fr) * 72 + ks * 32 + fq * 8);
                acc[n] = __builtin_amdgcn_mfma_f32_16x16x32_bf16(af, bf8, acc[n], 0, 0, 0);
            }
        }
    }
#pragma unroll
    for (int n = 0; n < 2; ++n)
#pragma unroll
        for (int j = 0; j < 4; ++j) {
            int row = row0 + wr * 16 + fq * 4 + j;
            int col = col0 + wc * 32 + n * 16 + fr;
            float v = acc[n][j] + bias[col];
            unsigned int ow = f2bf(elu1(v));
            unsigned int pr = __shfl_xor(ow, 1, 64);
            if (!(fr & 1))
                dev_st((unsigned int*)(p.Z2 + row * HID + z * FEAT + col), ow | (pr << 16));
        }
}

// ---------------------------------------------------------------------------
// S3: bids 0..127: obs head 32x32 tiles (16x8) -> out, Xbuf, sq-loss.
//     bids 128..135: reward head (64 rows each). bids 136..143: act copy.
// ---------------------------------------------------------------------------
__device__ __forceinline__ void s3_stage(const Params& p, unsigned short* lds, int t) {
    const int tid = threadIdx.x, lane = tid & 63, wv = tid >> 6;
    const int wr = wv & 1, wc = wv >> 1, fr = lane & 15, fq = lane >> 4;
    const int bid = blockIdx.x;

    if (bid < 128) {
        const int row0 = (bid >> 3) * 32, col0 = (bid & 7) * 32;
        unsigned short* ldsA = lds;             // 32 x 72
        unsigned short* ldsB = lds + 32 * 72;   // 32 x 72
        floatx4 acc = {0.f, 0.f, 0.f, 0.f};

        const unsigned short* Ag = p.Z2 + (size_t)row0 * HID;   // obs half
        const unsigned short* Bg = p.W2o + (size_t)col0 * FEAT;
        uint4 ra, rb;
        ra = dev_ld4(Ag + (size_t)(tid >> 3) * HID + ((tid & 7) << 3));
        rb = *(const uint4*)(Bg + (size_t)(tid >> 3) * FEAT + ((tid & 7) << 3));
        for (int k0 = 0; k0 < 512; k0 += 64) {
            __syncthreads();
            *(uint4*)(ldsA + (tid >> 3) * 72 + ((tid & 7) << 3)) = ra;
            *(uint4*)(ldsB + (tid >> 3) * 72 + ((tid & 7) << 3)) = rb;
            __syncthreads();
            if (k0 + 64 < 512) {
                ra = dev_ld4(Ag + (size_t)(tid >> 3) * HID + k0 + 64 + ((tid & 7) << 3));
                rb = *(const uint4*)(Bg + (size_t)(tid >> 3) * FEAT + k0 + 64 + ((tid & 7) << 3));
            }
#pragma unroll
            for (int ks = 0; ks < 2; ++ks) {
                short8 af = *(const short8*)(ldsA + (wr * 16 + fr) * 72 + ks * 32 + fq * 8);
                short8 bf8 = *(const short8*)(ldsB + (wc * 16 + fr) * 72 + ks * 32 + fq * 8);
                acc = __builtin_amdgcn_mfma_f32_16x16x32_bf16(af, bf8, acc, 0, 0, 0);
            }
        }
        float lsum = 0.f;
#pragma unroll
        for (int j = 0; j < 4; ++j) {
            int row = row0 + wr * 16 + fq * 4 + j;
            int col = col0 + wc * 16 + fr;
            float mval = acc[j] + p.b2o[col];
            size_t oidx = (size_t)t * BATCH * OBS_DIM + (size_t)row * OBS_DIM + col;
            p.out[1 + oidx] = mval;
            unsigned int ow = f2bf(mval);
            unsigned int pr = __shfl_xor(ow, 1, 64);
            if (!(fr & 1))
                dev_st((unsigned int*)(p.Xbuf + row * KIH + col), ow | (pr << 16));
            float d = p.obs[oidx] - mval;
            lsum += d * d;
        }
#pragma unroll
        for (int off = 32; off > 0; off >>= 1) lsum += __shfl_down(lsum, off, 64);
        if (lane == 0) atomicAdd(p.accum + 0, lsum);
    } else if (bid < 136) {
        // reward head: 64 rows, 4 waves x 16 rows
        const int r0 = (bid - 128) * 64;
        short8 wv8 = *(const short8*)(p.w2r + lane * 8);
        float wsum = 0.f;
        for (int i = 0; i < 16; ++i) {
            int row = r0 + wv * 16 + i;
            const unsigned int* zp =
                (const unsigned int*)(p.Z2 + (size_t)row * HID + FEAT) + lane * 4;
            float s = 0.f;
#pragma unroll
            for (int k = 0; k < 4; ++k) {
                unsigned int u = dev_ld(zp + k);
                s += bf2f(u & 0xFFFFu) * bf2f((unsigned short)wv8[2 * k]);
                s += bf2f(u >> 16)     * bf2f((unsigned short)wv8[2 * k + 1]);
            }
#pragma unroll
            for (int off = 32; off > 0; off >>= 1) s += __shfl_down(s, off, 64);
            if (lane == 0) {
                float m = s + p.b2r[0];
                p.out[1 + (size_t)T_STEPS * BATCH * OBS_DIM + (size_t)t * BATCH + row] = m;
                float d = p.reward[(size_t)t * BATCH + row] - m;
                wsum += d * d;
            }
        }
        if (lane == 0) atomicAdd(p.accum + 1, wsum);
    } else if (bid < 144) {
        const int r0 = (bid - 136) * 64;
        for (int e = tid; e < 64 * 16; e += 256) {
            int row = r0 + (e >> 4), cp = (e & 15) * 2;
            const float* ap = p.action + ((size_t)t * BATCH + row) * ACT_DIM + cp;
            unsigned int lo = f2bf(ap[0]);
            unsigned int hi = f2bf(ap[1]);
            dev_st((unsigned int*)(p.Xbuf + row * KIH + OBS_DIM + cp), lo | (hi << 16));
        }
    }
}

// ---------------------------------------------------------------------------
// S4: gi = Xbuf[512 x 288] @ Wih^T (3 gates), fused GRU gates -> h, hbf.
// 256 blocks: 8 row-tiles(64) x 32 col-tiles(32 hid-cols, all 3 gates).
// K=288, BK=96 (3 iters).
// ---------------------------------------------------------------------------
__device__ __forceinline__ void s4_stage(const Params& p, unsigned short* lds, int use_gh) {
    const int tid = threadIdx.x, lane = tid & 63, wv = tid >> 6;
    const int wr = wv & 1, wc = wv >> 1, fr = lane & 15, fq = lane >> 4;
    const int bid = blockIdx.x;
    const int row0 = (bid >> 5) * 64, col0 = (bid & 31) * 32;
    unsigned short* ldsA = lds;              // 64 x 104
    unsigned short* ldsB = lds + 64 * 104;   // 96 x 104

    floatx4 acc[3][2];
    floatx4 z4 = {0.f, 0.f, 0.f, 0.f};
#pragma unroll
    for (int g = 0; g < 3; ++g) { acc[g][0] = z4; acc[g][1] = z4; }

    for (int k0 = 0; k0 < KIH; k0 += 96) {
        __syncthreads();
        for (int c = tid; c < 768; c += 256) {
            int r = c / 12, ko = (c - r * 12) * 8;
            *(uint4*)(ldsA + r * 104 + ko) =
                dev_ld4(p.Xbuf + (size_t)(row0 + r) * KIH + k0 + ko);
        }
        for (int c = tid; c < 1152; c += 256) {
            int r = c / 12, ko = (c - r * 12) * 8;
            int g = r >> 5, cr = r & 31;
            *(uint4*)(ldsB + r * 104 + ko) =
                *(const uint4*)(p.Wih + (size_t)(g * HID + col0 + cr) * KIH + k0 + ko);
        }
        __syncthreads();
#pragma unroll
        for (int ks = 0; ks < 3; ++ks) {
            short8 af[2];
#pragma unroll
            for (int m = 0; m < 2; ++m)
                af[m] = *(const short8*)(ldsA + (wr * 32 + m * 16 + fr) * 104 + ks * 32 + fq * 8);
#pragma unroll
            for (int g = 0; g < 3; ++g) {
                short8 bf8 = *(const short8*)(ldsB + (g * 32 + wc * 16 + fr) * 104 + ks * 32 + fq * 8);
#pragma unroll
                for (int m = 0; m < 2; ++m)
                    acc[g][m] = __builtin_amdgcn_mfma_f32_16x16x32_bf16(
                        af[m], bf8, acc[g][m], 0, 0, 0);
            }
        }
    }
#pragma unroll
    for (int m = 0; m < 2; ++m)
#pragma unroll
        for (int j = 0; j < 4; ++j) {
            int row = row0 + wr * 32 + m * 16 + fq * 4 + j;
            int col = col0 + wc * 16 + fr;
            float gr = acc[0][m][j] + p.b_ih[col];
            float gz = acc[1][m][j] + p.b_ih[HID + col];
            float gn = acc[2][m][j] + p.b_ih[2 * HID + col];
            float hr, hz, hn, hp;
            if (use_gh) {
                hr = dev_ldf(p.GH + (size_t)row * GDIM + col);
                hz = dev_ldf(p.GH + (size_t)row * GDIM + HID + col);
                hn = dev_ldf(p.GH + (size_t)row * GDIM + 2 * HID + col);
                hp = dev_ldf(p.h + (size_t)row * HID + col);
            } else {
                hr = p.b_hh[col];
                hz = p.b_hh[HID + col];
                hn = p.b_hh[2 * HID + col];
                hp = 0.f;
            }
            float r  = sigm(gr + hr);
            float z  = sigm(gz + hz);
            float nn = tanhf(gn + r * hn);
            float hv = (1.f - z) * nn + z * hp;
            dev_stf(p.h + (size_t)row * HID + col, hv);
            unsigned int ow = f2bf(hv);
            unsigned int pr = __shfl_xor(ow, 1, 64);
            if (!(fr & 1))
                dev_st((unsigned int*)(p.hbf + row * HID + col), ow | (pr << 16));
        }
}

// ---------------------------------------------------------------------------
// Persistent rollout kernel: plain launch; all 256 blocks co-resident
// (33 KB LDS -> 4 blocks/CU capacity, 1 needed). Grid sync via gbar.
// ---------------------------------------------------------------------------
__global__ __launch_bounds__(256, 1) void k_persist(Params p) {
    __shared__ unsigned short lds[16640];   // max stage footprint (S4: 33.3 KB)

    // h0 = GRU([obs0, 0], 0); Xbuf pre-filled by k_init
    s4_stage(p, lds, 0);
    gbar(p.bar);

    for (int t = 0; t < T_STEPS; ++t) {
        s1_stage(p, lds);
        gbar(p.bar);
        s2_stage(p, lds);
        gbar(p.bar);
        s3_stage(p, lds, t);
        gbar(p.bar);
        if (t < T_STEPS - 1) {
            s4_stage(p, lds, 1);
            gbar(p.bar);
        }
    }
    if (blockIdx.x == 0 && threadIdx.x == 0) {
        const float inv = 1.f / (float)(T_STEPS * BATCH);
        float a0 = dev_ldf(p.accum + 0);
        float a1 = dev_ldf(p.accum + 1);
        p.out[0] = 0.5f * a0 * inv + 128.f * LOG2PI
                 + 0.5f * a1 * inv + 0.5f * LOG2PI;
    }
}

// ---------------------------------------------------------------------------
__global__ void k_convert(
    const float* __restrict__ ow0, const float* __restrict__ rw0,
    const float* __restrict__ whh, const float* __restrict__ wih,
    const float* __restrict__ ow1, const float* __restrict__ rw1,
    const float* __restrict__ ow2, const float* __restrict__ rw2,
    const float* __restrict__ ob0, const float* __restrict__ rb0,
    const float* __restrict__ bhh,
    unsigned short* __restrict__ Ws1, unsigned short* __restrict__ Wih,
    unsigned short* __restrict__ W1o, unsigned short* __restrict__ W1r,
    unsigned short* __restrict__ W2o, unsigned short* __restrict__ w2r,
    float* __restrict__ bias_s1)
{
    const int i0 = blockIdx.x * 256 + threadIdx.x;
    const int stride = gridDim.x * 256;
    for (int i = i0; i < 4096 * 1024; i += stride) {
        int row = i >> 10;
        float v = (row < 512) ? ow0[i]
                : (row < 1024) ? rw0[i - 512 * 1024]
                               : whh[i - 1024 * 1024];
        Ws1[i] = (unsigned short)f2bf(v);
    }
    for (int i = i0; i < GDIM * KIH; i += stride) Wih[i] = (unsigned short)f2bf(wih[i]);
    for (int i = i0; i < FEAT * FEAT; i += stride) {
        W1o[i] = (unsigned short)f2bf(ow1[i]);
        W1r[i] = (unsigned short)f2bf(rw1[i]);
    }
    for (int i = i0; i < OBS_DIM * FEAT; i += stride) W2o[i] = (unsigned short)f2bf(ow2[i]);
    for (int i = i0; i < FEAT; i += stride) w2r[i] = (unsigned short)f2bf(rw2[i]);
    for (int i = i0; i < 4096; i += stride)
        bias_s1[i] = (i < 512) ? ob0[i] : (i < 1024) ? rb0[i - 512] : bhh[i - 1024];
}

__global__ void k_init(const float* __restrict__ obs,
                       unsigned short* __restrict__ Xbuf,
                       float* __restrict__ accum,
                       int* __restrict__ bar)
{
    int i = blockIdx.x * 256 + threadIdx.x;
    if (i < BATCH * KIH) {
        int row = i / KIH, col = i - row * KIH;
        Xbuf[i] = (col < OBS_DIM) ? (unsigned short)f2bf(obs[row * OBS_DIM + col])
                                  : (unsigned short)0;
    }
    if (i < 2)  accum[i] = 0.f;
    if (i < 64) bar[i] = 0;
}

// ---------------------------------------------------------------------------
extern "C" void kernel_launch(void* const* d_in, const int* in_sizes, int n_in,
                              void* d_out, int out_size, void* d_ws, size_t ws_size,
                              hipStream_t stream)
{
    const float* obs      = (const float*)d_in[0];
    const float* action   = (const float*)d_in[1];
    const float* reward   = (const float*)d_in[2];
    const float* gru_w_ih = (const float*)d_in[3];
    const float* gru_w_hh = (const float*)d_in[4];
    const float* gru_b_ih = (const float*)d_in[5];
    const float* gru_b_hh = (const float*)d_in[6];
    const float* obs_w0   = (const float*)d_in[7];
    const float* obs_b0   = (const float*)d_in[8];
    const float* obs_w1   = (const float*)d_in[9];
    const float* obs_b1   = (const float*)d_in[10];
    const float* obs_w2   = (const float*)d_in[11];
    const float* obs_b2   = (const float*)d_in[12];
    const float* rew_w0   = (const float*)d_in[13];
    const float* rew_b0   = (const float*)d_in[14];
    const float* rew_w1   = (const float*)d_in[15];
    const float* rew_b1   = (const float*)d_in[16];
    const float* rew_w2   = (const float*)d_in[17];
    const float* rew_b2   = (const float*)d_in[18];

    char* ws = (char*)d_ws;
    auto alloc = [&](size_t bytes) -> char* {
        char* pr = ws;
        ws += (bytes + 255) & ~(size_t)255;
        return pr;
    };
    unsigned short* Ws1     = (unsigned short*)alloc((size_t)4096 * 1024 * 2);
    unsigned short* Wih     = (unsigned short*)alloc((size_t)GDIM * KIH * 2);
    unsigned short* W1o     = (unsigned short*)alloc((size_t)FEAT * FEAT * 2);
    unsigned short* W1r     = (unsigned short*)alloc((size_t)FEAT * FEAT * 2);
    unsigned short* W2o     = (unsigned short*)alloc((size_t)OBS_DIM * FEAT * 2);
    unsigned short* w2r     = (unsigned short*)alloc((size_t)FEAT * 2);
    float*          bias_s1 = (float*)alloc((size_t)4096 * 4);
    unsigned short* Z1      = (unsigned short*)alloc((size_t)BATCH * HID * 2);
    unsigned short* Z2      = (unsigned short*)alloc((size_t)BATCH * HID * 2);
    float*          GH      = (float*)alloc((size_t)BATCH * GDIM * 4);
    unsigned short* Xbuf    = (unsigned short*)alloc((size_t)BATCH * KIH * 2);
    float*          h       = (float*)alloc((size_t)BATCH * HID * 4);
    unsigned short* hbf     = (unsigned short*)alloc((size_t)BATCH * HID * 2);
    float*          accum   = (float*)alloc(256);
    int*            bar     = (int*)alloc(256);

    dim3 blk(256);

    k_convert<<<dim3(1024), blk, 0, stream>>>(
        obs_w0, rew_w0, gru_w_hh, gru_w_ih, obs_w1, rew_w1, obs_w2, rew_w2,
        obs_b0, rew_b0, gru_b_hh, Ws1, Wih, W1o, W1r, W2o, w2r, bias_s1);

    k_init<<<dim3((BATCH * KIH + 255) / 256), blk, 0, stream>>>(obs, Xbuf, accum, bar);

    Params hp;
    hp.obs = obs; hp.action = action; hp.reward = reward;
    hp.b_ih = gru_b_ih; hp.b_hh = gru_b_hh;
    hp.b1o = obs_b1; hp.b1r = rew_b1; hp.b2o = obs_b2; hp.b2r = rew_b2;
    hp.Ws1 = Ws1; hp.Wih = Wih; hp.W1o = W1o; hp.W1r = W1r;
    hp.W2o = W2o; hp.w2r = w2r; hp.bias_s1 = bias_s1;
    hp.Z1 = Z1; hp.Z2 = Z2; hp.Xbuf = Xbuf; hp.hbf = hbf;
    hp.GH = GH; hp.h = h; hp.accum = accum; hp.out = (float*)d_out;
    hp.bar = bar;

    k_persist<<<dim3(NBLK), blk, 0, stream>>>(hp);
}

// Round 5
// 6633.518 us; speedup vs baseline: 1.2650x; 1.0933x over previous
//
#include <hip/hip_runtime.h>
#include <stdint.h>

#define T_STEPS 64
#define BATCH   512
#define OBS_DIM 256
#define ACT_DIM 32
#define HID     1024
#define FEAT    512
#define GDIM    3072
#define KIH     288
#define NBLK    256
#define GMEMB   32          // blocks per group
#define LOG2PI  1.8378770664093453f

typedef __attribute__((ext_vector_type(8))) short  short8;   // 8 bf16
typedef __attribute__((ext_vector_type(4))) float  floatx4;  // MFMA C/D frag

__device__ __forceinline__ float bf2f(unsigned int u) {
    return __uint_as_float(u << 16);
}
__device__ __forceinline__ unsigned int f2bf(float f) {
    unsigned int u = __float_as_uint(f);
    return (u + 0x7FFFu + ((u >> 16) & 1u)) >> 16;  // RNE
}
__device__ __forceinline__ float elu1(float x)  { return x > 0.f ? x : expm1f(x); }
__device__ __forceinline__ float sigm(float x)  { return 1.f / (1.f + expf(-x)); }

// Device-coherent (cache-bypassing) accessors for mutable inter-stage data.
__device__ __forceinline__ unsigned int dev_ld(const unsigned int* p) {
    return __hip_atomic_load(p, __ATOMIC_RELAXED, __HIP_MEMORY_SCOPE_AGENT);
}
__device__ __forceinline__ void dev_st(unsigned int* p, unsigned int v) {
    __hip_atomic_store(p, v, __ATOMIC_RELAXED, __HIP_MEMORY_SCOPE_AGENT);
}
__device__ __forceinline__ uint4 dev_ld4(const unsigned short* p) {
    const unsigned int* q = (const unsigned int*)p;
    uint4 r;
    r.x = dev_ld(q + 0); r.y = dev_ld(q + 1);
    r.z = dev_ld(q + 2); r.w = dev_ld(q + 3);
    return r;
}
__device__ __forceinline__ float dev_ldf(const float* p) {
    return __uint_as_float(dev_ld((const unsigned int*)p));
}
__device__ __forceinline__ void dev_stf(float* p, float v) {
    dev_st((unsigned int*)p, __float_as_uint(v));
}

struct Params {
    const float* obs; const float* action; const float* reward;
    const float* b_ih; const float* b_hh;
    const float* b1o; const float* b1r; const float* b2o; const float* b2r;
    const unsigned short* Ws1; const unsigned short* Wih;
    const unsigned short* W1o; const unsigned short* W1r;
    const unsigned short* W2o; const unsigned short* w2r;
    const float* bias_s1;
    unsigned short* Z1; unsigned short* Z2; unsigned short* Xbuf; unsigned short* hbf;
    float* GH; float* h; float* accum; float* out;
    int* bar;
};

// ---------------------------------------------------------------------------
// Group barrier: `members` arrivals, monotonic epoch counter (no reset race),
// relaxed agent atomics, s_sleep backoff. cnt/gen on separate 256B lines.
// ---------------------------------------------------------------------------
__device__ __forceinline__ void gbar(int* cnt, int* gen, int& epoch, int members) {
    __syncthreads();     // drains vmcnt(0): stage stores are at the coherence pt
    if (threadIdx.x == 0) {
        __builtin_amdgcn_fence(__ATOMIC_RELEASE, "workgroup");
        epoch++;
        int prev = __hip_atomic_fetch_add(cnt, 1, __ATOMIC_RELAXED,
                                          __HIP_MEMORY_SCOPE_AGENT);
        if (prev == members * epoch - 1) {
            __hip_atomic_store(gen, epoch, __ATOMIC_RELAXED,
                               __HIP_MEMORY_SCOPE_AGENT);
        } else {
            while (__hip_atomic_load(gen, __ATOMIC_RELAXED,
                                     __HIP_MEMORY_SCOPE_AGENT) < epoch)
                __builtin_amdgcn_s_sleep(8);
        }
        __builtin_amdgcn_fence(__ATOMIC_ACQUIRE, "workgroup");
    }
    __syncthreads();
}

// ---------------------------------------------------------------------------
// S1 (per group g, member m): C[64 x 4096] = hbf[g] @ Ws1^T + bias.
// block tile 64 x 128 (col0 = m*128), K=1024, BK=64, reg-prefetch dbuf.
// cols<1024 -> elu -> Z1 ; cols>=1024 -> GH.
// ---------------------------------------------------------------------------
__device__ __forceinline__ void s1_stage(const Params& p, unsigned short* lds,
                                         int g, int m) {
    const int tid = threadIdx.x, lane = tid & 63, wv = tid >> 6;
    const int wr = wv & 1, wc = wv >> 1, fr = lane & 15, fq = lane >> 4;
    const int rowg = g * 64;
    const int col0 = m * 128;
    unsigned short* ldsA = lds;             // 64 x 72
    unsigned short* ldsB = lds + 64 * 72;   // 128 x 72

    floatx4 acc[2][4];
    floatx4 z4 = {0.f, 0.f, 0.f, 0.f};
#pragma unroll
    for (int mi = 0; mi < 2; ++mi)
#pragma unroll
        for (int n = 0; n < 4; ++n) acc[mi][n] = z4;

    const unsigned short* Ag = p.hbf + (size_t)rowg * HID;
    const unsigned short* Bg = p.Ws1 + (size_t)col0 * HID;
    uint4 ra[2], rb[4];
#pragma unroll
    for (int i = 0; i < 2; ++i) { int c = tid + 256 * i;
        ra[i] = dev_ld4(Ag + (size_t)(c >> 3) * HID + ((c & 7) << 3)); }
#pragma unroll
    for (int i = 0; i < 4; ++i) { int c = tid + 256 * i;
        rb[i] = *(const uint4*)(Bg + (size_t)(c >> 3) * HID + ((c & 7) << 3)); }

    for (int k0 = 0; k0 < 1024; k0 += 64) {
        __syncthreads();
#pragma unroll
        for (int i = 0; i < 2; ++i) { int c = tid + 256 * i;
            *(uint4*)(ldsA + (c >> 3) * 72 + ((c & 7) << 3)) = ra[i]; }
#pragma unroll
        for (int i = 0; i < 4; ++i) { int c = tid + 256 * i;
            *(uint4*)(ldsB + (c >> 3) * 72 + ((c & 7) << 3)) = rb[i]; }
        __syncthreads();
        if (k0 + 64 < 1024) {
#pragma unroll
            for (int i = 0; i < 2; ++i) { int c = tid + 256 * i;
                ra[i] = dev_ld4(Ag + (size_t)(c >> 3) * HID + k0 + 64 + ((c & 7) << 3)); }
#pragma unroll
            for (int i = 0; i < 4; ++i) { int c = tid + 256 * i;
                rb[i] = *(const uint4*)(Bg + (size_t)(c >> 3) * HID + k0 + 64 + ((c & 7) << 3)); }
        }
#pragma unroll
        for (int ks = 0; ks < 2; ++ks) {
            short8 af[2], bf8[4];
#pragma unroll
            for (int mi = 0; mi < 2; ++mi)
                af[mi] = *(const short8*)(ldsA + (wr * 32 + mi * 16 + fr) * 72 + ks * 32 + fq * 8);
#pragma unroll
            for (int n = 0; n < 4; ++n)
                bf8[n] = *(const short8*)(ldsB + (wc * 64 + n * 16 + fr) * 72 + ks * 32 + fq * 8);
#pragma unroll
            for (int mi = 0; mi < 2; ++mi)
#pragma unroll
                for (int n = 0; n < 4; ++n)
                    acc[mi][n] = __builtin_amdgcn_mfma_f32_16x16x32_bf16(
                        af[mi], bf8[n], acc[mi][n], 0, 0, 0);
        }
    }
    const bool isZ1 = (col0 < 1024);
#pragma unroll
    for (int mi = 0; mi < 2; ++mi)
#pragma unroll
        for (int n = 0; n < 4; ++n)
#pragma unroll
            for (int j = 0; j < 4; ++j) {
                int row = rowg + wr * 32 + mi * 16 + fq * 4 + j;
                int col = col0 + wc * 64 + n * 16 + fr;
                float v = acc[mi][n][j] + p.bias_s1[col];
                if (isZ1) {
                    unsigned int ow = f2bf(elu1(v));
                    unsigned int pr = __shfl_xor(ow, 1, 64);
                    if (!(fr & 1))
                        dev_st((unsigned int*)(p.Z1 + row * HID + col), ow | (pr << 16));
                } else {
                    dev_stf(p.GH + (size_t)row * GDIM + (col - 1024), v);
                }
            }
}

// ---------------------------------------------------------------------------
// S2: Z2[g rows, z*512+col] = elu(Z1[g rows, z half] @ W1z^T + b1z).
// member m: z = m>>4, col0 = (m&15)*32. block tile 64x32, K=512, BK=64.
// ---------------------------------------------------------------------------
__device__ __forceinline__ void s2_stage(const Params& p, unsigned short* lds,
                                         int g, int m) {
    const int tid = threadIdx.x, lane = tid & 63, wv = tid >> 6;
    const int wr = wv & 1, wc = wv >> 1, fr = lane & 15, fq = lane >> 4;
    const int rowg = g * 64;
    const int z = m >> 4, col0 = (m & 15) * 32;
    unsigned short* ldsA = lds;             // 64 x 72
    unsigned short* ldsB = lds + 64 * 72;   // 32 x 72

    floatx4 acc[2];
    floatx4 z4 = {0.f, 0.f, 0.f, 0.f};
    acc[0] = z4; acc[1] = z4;

    const unsigned short* Ag = p.Z1 + (size_t)rowg * HID + z * FEAT;
    const unsigned short* Bg = (z ? p.W1r : p.W1o) + (size_t)col0 * FEAT;
    const float* bias = z ? p.b1r : p.b1o;

    uint4 ra[2], rb;
#pragma unroll
    for (int i = 0; i < 2; ++i) { int c = tid + 256 * i;
        ra[i] = dev_ld4(Ag + (size_t)(c >> 3) * HID + ((c & 7) << 3)); }
    rb = *(const uint4*)(Bg + (size_t)(tid >> 3) * FEAT + ((tid & 7) << 3));

    for (int k0 = 0; k0 < 512; k0 += 64) {
        __syncthreads();
#pragma unroll
        for (int i = 0; i < 2; ++i) { int c = tid + 256 * i;
            *(uint4*)(ldsA + (c >> 3) * 72 + ((c & 7) << 3)) = ra[i]; }
        *(uint4*)(ldsB + (tid >> 3) * 72 + ((tid & 7) << 3)) = rb;
        __syncthreads();
        if (k0 + 64 < 512) {
#pragma unroll
            for (int i = 0; i < 2; ++i) { int c = tid + 256 * i;
                ra[i] = dev_ld4(Ag + (size_t)(c >> 3) * HID + k0 + 64 + ((c & 7) << 3)); }
            rb = *(const uint4*)(Bg + (size_t)(tid >> 3) * FEAT + k0 + 64 + ((tid & 7) << 3));
        }
#pragma unroll
        for (int ks = 0; ks < 2; ++ks) {
            short8 bf8 = *(const short8*)(ldsB + (wc * 16 + fr) * 72 + ks * 32 + fq * 8);
#pragma unroll
            for (int mi = 0; mi < 2; ++mi) {
                short8 af = *(const short8*)(ldsA + (wr * 32 + mi * 16 + fr) * 72 + ks * 32 + fq * 8);
                acc[mi] = __builtin_amdgcn_mfma_f32_16x16x32_bf16(af, bf8, acc[mi], 0, 0, 0);
            }
        }
    }
#pragma unroll
    for (int mi = 0; mi < 2; ++mi)
#pragma unroll
        for (int j = 0; j < 4; ++j) {
            int row = rowg + wr * 32 + mi * 16 + fq * 4 + j;
            int col = col0 + wc * 16 + fr;
            float v = acc[mi][j] + bias[col];
            unsigned int ow = f2bf(elu1(v));
            unsigned int pr = __shfl_xor(ow, 1, 64);
            if (!(fr & 1))
                dev_st((unsigned int*)(p.Z2 + row * HID + z * FEAT + col), ow | (pr << 16));
        }
}

// ---------------------------------------------------------------------------
// S3: m<8: obs head tile 64x32 (col0=m*32), K=512 -> out, Xbuf, sq-loss.
//     m==8: reward head (64 rows). m==9: act copy. m>=10: idle.
// ---------------------------------------------------------------------------
__device__ __forceinline__ void s3_stage(const Params& p, unsigned short* lds,
                                         int g, int m, int t) {
    const int tid = threadIdx.x, lane = tid & 63, wv = tid >> 6;
    const int wr = wv & 1, wc = wv >> 1, fr = lane & 15, fq = lane >> 4;
    const int rowg = g * 64;

    if (m < 8) {
        const int col0 = m * 32;
        unsigned short* ldsA = lds;             // 64 x 72
        unsigned short* ldsB = lds + 64 * 72;   // 32 x 72
        floatx4 acc[2];
        floatx4 z4 = {0.f, 0.f, 0.f, 0.f};
        acc[0] = z4; acc[1] = z4;

        const unsigned short* Ag = p.Z2 + (size_t)rowg * HID;   // obs half
        const unsigned short* Bg = p.W2o + (size_t)col0 * FEAT;
        uint4 ra[2], rb;
#pragma unroll
        for (int i = 0; i < 2; ++i) { int c = tid + 256 * i;
            ra[i] = dev_ld4(Ag + (size_t)(c >> 3) * HID + ((c & 7) << 3)); }
        rb = *(const uint4*)(Bg + (size_t)(tid >> 3) * FEAT + ((tid & 7) << 3));

        for (int k0 = 0; k0 < 512; k0 += 64) {
            __syncthreads();
#pragma unroll
            for (int i = 0; i < 2; ++i) { int c = tid + 256 * i;
                *(uint4*)(ldsA + (c >> 3) * 72 + ((c & 7) << 3)) = ra[i]; }
            *(uint4*)(ldsB + (tid >> 3) * 72 + ((tid & 7) << 3)) = rb;
            __syncthreads();
            if (k0 + 64 < 512) {
#pragma unroll
                for (int i = 0; i < 2; ++i) { int c = tid + 256 * i;
                    ra[i] = dev_ld4(Ag + (size_t)(c >> 3) * HID + k0 + 64 + ((c & 7) << 3)); }
                rb = *(const uint4*)(Bg + (size_t)(tid >> 3) * FEAT + k0 + 64 + ((tid & 7) << 3));
            }
#pragma unroll
            for (int ks = 0; ks < 2; ++ks) {
                short8 bf8 = *(const short8*)(ldsB + (wc * 16 + fr) * 72 + ks * 32 + fq * 8);
#pragma unroll
                for (int mi = 0; mi < 2; ++mi) {
                    short8 af = *(const short8*)(ldsA + (wr * 32 + mi * 16 + fr) * 72 + ks * 32 + fq * 8);
                    acc[mi] = __builtin_amdgcn_mfma_f32_16x16x32_bf16(af, bf8, acc[mi], 0, 0, 0);
                }
            }
        }
        float lsum = 0.f;
#pragma unroll
        for (int mi = 0; mi < 2; ++mi)
#pragma unroll
            for (int j = 0; j < 4; ++j) {
                int row = rowg + wr * 32 + mi * 16 + fq * 4 + j;
                int col = col0 + wc * 16 + fr;
                float mval = acc[mi][j] + p.b2o[col];
                size_t oidx = (size_t)t * BATCH * OBS_DIM + (size_t)row * OBS_DIM + col;
                p.out[1 + oidx] = mval;
                unsigned int ow = f2bf(mval);
                unsigned int pr = __shfl_xor(ow, 1, 64);
                if (!(fr & 1))
                    dev_st((unsigned int*)(p.Xbuf + row * KIH + col), ow | (pr << 16));
                float d = p.obs[oidx] - mval;
                lsum += d * d;
            }
#pragma unroll
        for (int off = 32; off > 0; off >>= 1) lsum += __shfl_down(lsum, off, 64);
        if (lane == 0) atomicAdd(p.accum + 0, lsum);
    } else if (m == 8) {
        short8 wv8 = *(const short8*)(p.w2r + lane * 8);
        float wsum = 0.f;
        for (int i = 0; i < 16; ++i) {
            int row = rowg + wv * 16 + i;
            const unsigned int* zp =
                (const unsigned int*)(p.Z2 + (size_t)row * HID + FEAT) + lane * 4;
            float s = 0.f;
#pragma unroll
            for (int k = 0; k < 4; ++k) {
                unsigned int u = dev_ld(zp + k);
                s += bf2f(u & 0xFFFFu) * bf2f((unsigned int)(unsigned short)wv8[2 * k]);
                s += bf2f(u >> 16)     * bf2f((unsigned int)(unsigned short)wv8[2 * k + 1]);
            }
#pragma unroll
            for (int off = 32; off > 0; off >>= 1) s += __shfl_down(s, off, 64);
            if (lane == 0) {
                float mm = s + p.b2r[0];
                p.out[1 + (size_t)T_STEPS * BATCH * OBS_DIM + (size_t)t * BATCH + row] = mm;
                float d = p.reward[(size_t)t * BATCH + row] - mm;
                wsum += d * d;
            }
        }
        if (lane == 0) atomicAdd(p.accum + 1, wsum);
    } else if (m == 9) {
        for (int e = tid; e < 64 * 16; e += 256) {
            int row = rowg + (e >> 4), cp = (e & 15) * 2;
            const float* ap = p.action + ((size_t)t * BATCH + row) * ACT_DIM + cp;
            unsigned int lo = f2bf(ap[0]);
            unsigned int hi = f2bf(ap[1]);
            dev_st((unsigned int*)(p.Xbuf + row * KIH + OBS_DIM + cp), lo | (hi << 16));
        }
    }
}

// ---------------------------------------------------------------------------
// S4: gi = Xbuf[g rows] @ Wih^T (3 gates) -> GRU gates -> h, hbf.
// member m: col0 = m*32 (32 hid-cols, all 3 gates). K=288, BK=96.
// ---------------------------------------------------------------------------
__device__ __forceinline__ void s4_stage(const Params& p, unsigned short* lds,
                                         int g, int m, int use_gh) {
    const int tid = threadIdx.x, lane = tid & 63, wv = tid >> 6;
    const int wr = wv & 1, wc = wv >> 1, fr = lane & 15, fq = lane >> 4;
    const int rowg = g * 64;
    const int col0 = m * 32;
    unsigned short* ldsA = lds;              // 64 x 104
    unsigned short* ldsB = lds + 64 * 104;   // 96 x 104

    floatx4 acc[3][2];
    floatx4 z4 = {0.f, 0.f, 0.f, 0.f};
#pragma unroll
    for (int g3 = 0; g3 < 3; ++g3) { acc[g3][0] = z4; acc[g3][1] = z4; }

    for (int k0 = 0; k0 < KIH; k0 += 96) {
        __syncthreads();
        for (int c = tid; c < 768; c += 256) {
            int r = c / 12, ko = (c - r * 12) * 8;
            *(uint4*)(ldsA + r * 104 + ko) =
                dev_ld4(p.Xbuf + (size_t)(rowg + r) * KIH + k0 + ko);
        }
        for (int c = tid; c < 1152; c += 256) {
            int r = c / 12, ko = (c - r * 12) * 8;
            int g3 = r >> 5, cr = r & 31;
            *(uint4*)(ldsB + r * 104 + ko) =
                *(const uint4*)(p.Wih + (size_t)(g3 * HID + col0 + cr) * KIH + k0 + ko);
        }
        __syncthreads();
#pragma unroll
        for (int ks = 0; ks < 3; ++ks) {
            short8 af[2];
#pragma unroll
            for (int mi = 0; mi < 2; ++mi)
                af[mi] = *(const short8*)(ldsA + (wr * 32 + mi * 16 + fr) * 104 + ks * 32 + fq * 8);
#pragma unroll
            for (int g3 = 0; g3 < 3; ++g3) {
                short8 bf8 = *(const short8*)(ldsB + (g3 * 32 + wc * 16 + fr) * 104 + ks * 32 + fq * 8);
#pragma unroll
                for (int mi = 0; mi < 2; ++mi)
                    acc[g3][mi] = __builtin_amdgcn_mfma_f32_16x16x32_bf16(
                        af[mi], bf8, acc[g3][mi], 0, 0, 0);
            }
        }
    }
#pragma unroll
    for (int mi = 0; mi < 2; ++mi)
#pragma unroll
        for (int j = 0; j < 4; ++j) {
            int row = rowg + wr * 32 + mi * 16 + fq * 4 + j;
            int col = col0 + wc * 16 + fr;
            float gr = acc[0][mi][j] + p.b_ih[col];
            float gz = acc[1][mi][j] + p.b_ih[HID + col];
            float gn = acc[2][mi][j] + p.b_ih[2 * HID + col];
            float hr, hz, hn, hp;
            if (use_gh) {
                hr = dev_ldf(p.GH + (size_t)row * GDIM + col);
                hz = dev_ldf(p.GH + (size_t)row * GDIM + HID + col);
                hn = dev_ldf(p.GH + (size_t)row * GDIM + 2 * HID + col);
                hp = dev_ldf(p.h + (size_t)row * HID + col);
            } else {
                hr = p.b_hh[col];
                hz = p.b_hh[HID + col];
                hn = p.b_hh[2 * HID + col];
                hp = 0.f;
            }
            float r  = sigm(gr + hr);
            float z  = sigm(gz + hz);
            float nn = tanhf(gn + r * hn);
            float hv = (1.f - z) * nn + z * hp;
            dev_stf(p.h + (size_t)row * HID + col, hv);
            unsigned int ow = f2bf(hv);
            unsigned int pr = __shfl_xor(ow, 1, 64);
            if (!(fr & 1))
                dev_st((unsigned int*)(p.hbf + row * HID + col), ow | (pr << 16));
        }
}

// ---------------------------------------------------------------------------
// Persistent rollout: 8 independent groups of 32 blocks (64 batch rows each).
// Only intra-group barriers during the rollout; one global barrier at the end.
// ---------------------------------------------------------------------------
__global__ __launch_bounds__(256, 1) void k_persist(Params p) {
    __shared__ unsigned short lds[16640];   // max stage footprint (S4: 33.3 KB)

    const int bid = blockIdx.x;
    const int g = bid & 7;       // group (== XCD under round-robin heuristic)
    const int m = bid >> 3;      // member 0..31 within group
    int* gcnt = p.bar + g * 128;
    int* ggen = p.bar + g * 128 + 64;
    int epoch = 0;

    // h0 = GRU([obs0, 0], 0); Xbuf pre-filled by k_init
    s4_stage(p, lds, g, m, 0);
    gbar(gcnt, ggen, epoch, GMEMB);

    for (int t = 0; t < T_STEPS; ++t) {
        s1_stage(p, lds, g, m);
        gbar(gcnt, ggen, epoch, GMEMB);
        s2_stage(p, lds, g, m);
        gbar(gcnt, ggen, epoch, GMEMB);
        s3_stage(p, lds, g, m, t);
        gbar(gcnt, ggen, epoch, GMEMB);
        if (t < T_STEPS - 1) {
            s4_stage(p, lds, g, m, 1);
            gbar(gcnt, ggen, epoch, GMEMB);
        }
    }

    // final global barrier (all 256 blocks) before the loss write
    int* rcnt = p.bar + 8 * 128;
    int* rgen = p.bar + 8 * 128 + 64;
    int repoch = 0;
    gbar(rcnt, rgen, repoch, NBLK);

    if (bid == 0 && threadIdx.x == 0) {
        const float inv = 1.f / (float)(T_STEPS * BATCH);
        float a0 = dev_ldf(p.accum + 0);
        float a1 = dev_ldf(p.accum + 1);
        p.out[0] = 0.5f * a0 * inv + 128.f * LOG2PI
                 + 0.5f * a1 * inv + 0.5f * LOG2PI;
    }
}

// ---------------------------------------------------------------------------
__global__ void k_convert(
    const float* __restrict__ ow0, const float* __restrict__ rw0,
    const float* __restrict__ whh, const float* __restrict__ wih,
    const float* __restrict__ ow1, const float* __restrict__ rw1,
    const float* __restrict__ ow2, const float* __restrict__ rw2,
    const float* __restrict__ ob0, const float* __restrict__ rb0,
    const float* __restrict__ bhh,
    unsigned short* __restrict__ Ws1, unsigned short* __restrict__ Wih,
    unsigned short* __restrict__ W1o, unsigned short* __restrict__ W1r,
    unsigned short* __restrict__ W2o, unsigned short* __restrict__ w2r,
    float* __restrict__ bias_s1)
{
    const int i0 = blockIdx.x * 256 + threadIdx.x;
    const int stride = gridDim.x * 256;
    for (int i = i0; i < 4096 * 1024; i += stride) {
        int row = i >> 10;
        float v = (row < 512) ? ow0[i]
                : (row < 1024) ? rw0[i - 512 * 1024]
                               : whh[i - 1024 * 1024];
        Ws1[i] = (unsigned short)f2bf(v);
    }
    for (int i = i0; i < GDIM * KIH; i += stride) Wih[i] = (unsigned short)f2bf(wih[i]);
    for (int i = i0; i < FEAT * FEAT; i += stride) {
        W1o[i] = (unsigned short)f2bf(ow1[i]);
        W1r[i] = (unsigned short)f2bf(rw1[i]);
    }
    for (int i = i0; i < OBS_DIM * FEAT; i += stride) W2o[i] = (unsigned short)f2bf(ow2[i]);
    for (int i = i0; i < FEAT; i += stride) w2r[i] = (unsigned short)f2bf(rw2[i]);
    for (int i = i0; i < 4096; i += stride)
        bias_s1[i] = (i < 512) ? ob0[i] : (i < 1024) ? rb0[i - 512] : bhh[i - 1024];
}

__global__ void k_init(const float* __restrict__ obs,
                       unsigned short* __restrict__ Xbuf,
                       float* __restrict__ accum,
                       int* __restrict__ bar)
{
    int i = blockIdx.x * 256 + threadIdx.x;
    if (i < BATCH * KIH) {
        int row = i / KIH, col = i - row * KIH;
        Xbuf[i] = (col < OBS_DIM) ? (unsigned short)f2bf(obs[row * OBS_DIM + col])
                                  : (unsigned short)0;
    }
    if (i < 2)    accum[i] = 0.f;
    if (i < 1152) bar[i] = 0;
}

// ---------------------------------------------------------------------------
extern "C" void kernel_launch(void* const* d_in, const int* in_sizes, int n_in,
                              void* d_out, int out_size, void* d_ws, size_t ws_size,
                              hipStream_t stream)
{
    const float* obs      = (const float*)d_in[0];
    const float* action   = (const float*)d_in[1];
    const float* reward   = (const float*)d_in[2];
    const float* gru_w_ih = (const float*)d_in[3];
    const float* gru_w_hh = (const float*)d_in[4];
    const float* gru_b_ih = (const float*)d_in[5];
    const float* gru_b_hh = (const float*)d_in[6];
    const float* obs_w0   = (const float*)d_in[7];
    const float* obs_b0   = (const float*)d_in[8];
    const float* obs_w1   = (const float*)d_in[9];
    const float* obs_b1   = (const float*)d_in[10];
    const float* obs_w2   = (const float*)d_in[11];
    const float* obs_b2   = (const float*)d_in[12];
    const float* rew_w0   = (const float*)d_in[13];
    const float* rew_b0   = (const float*)d_in[14];
    const float* rew_w1   = (const float*)d_in[15];
    const float* rew_b1   = (const float*)d_in[16];
    const float* rew_w2   = (const float*)d_in[17];
    const float* rew_b2   = (const float*)d_in[18];

    char* ws = (char*)d_ws;
    auto alloc = [&](size_t bytes) -> char* {
        char* pr = ws;
        ws += (bytes + 255) & ~(size_t)255;
        return pr;
    };
    unsigned short* Ws1     = (unsigned short*)alloc((size_t)4096 * 1024 * 2);
    unsigned short* Wih     = (unsigned short*)alloc((size_t)GDIM * KIH * 2);
    unsigned short* W1o     = (unsigned short*)alloc((size_t)FEAT * FEAT * 2);
    unsigned short* W1r     = (unsigned short*)alloc((size_t)FEAT * FEAT * 2);
    unsigned short* W2o     = (unsigned short*)alloc((size_t)OBS_DIM * FEAT * 2);
    unsigned short* w2r     = (unsigned short*)alloc((size_t)FEAT * 2);
    float*          bias_s1 = (float*)alloc((size_t)4096 * 4);
    unsigned short* Z1      = (unsigned short*)alloc((size_t)BATCH * HID * 2);
    unsigned short* Z2      = (unsigned short*)alloc((size_t)BATCH * HID * 2);
    float*          GH      = (float*)alloc((size_t)BATCH * GDIM * 4);
    unsigned short* Xbuf    = (unsigned short*)alloc((size_t)BATCH * KIH * 2);
    float*          h       = (float*)alloc((size_t)BATCH * HID * 4);
    unsigned short* hbf     = (unsigned short*)alloc((size_t)BATCH * HID * 2);
    float*          accum   = (float*)alloc(256);
    int*            bar     = (int*)alloc(8192);

    dim3 blk(256);

    k_convert<<<dim3(1024), blk, 0, stream>>>(
        obs_w0, rew_w0, gru_w_hh, gru_w_ih, obs_w1, rew_w1, obs_w2, rew_w2,
        obs_b0, rew_b0, gru_b_hh, Ws1, Wih, W1o, W1r, W2o, w2r, bias_s1);

    k_init<<<dim3((BATCH * KIH + 255) / 256), blk, 0, stream>>>(obs, Xbuf, accum, bar);

    Params hp;
    hp.obs = obs; hp.action = action; hp.reward = reward;
    hp.b_ih = gru_b_ih; hp.b_hh = gru_b_hh;
    hp.b1o = obs_b1; hp.b1r = rew_b1; hp.b2o = obs_b2; hp.b2r = rew_b2;
    hp.Ws1 = Ws1; hp.Wih = Wih; hp.W1o = W1o; hp.W1r = W1r;
    hp.W2o = W2o; hp.w2r = w2r; hp.bias_s1 = bias_s1;
    hp.Z1 = Z1; hp.Z2 = Z2; hp.Xbuf = Xbuf; hp.hbf = hbf;
    hp.GH = GH; hp.h = h; hp.accum = accum; hp.out = (float*)d_out;
    hp.bar = bar;

    k_persist<<<dim3(NBLK), blk, 0, stream>>>(hp);
}

// Round 7
// 5122.640 us; speedup vs baseline: 1.6381x; 1.2949x over previous
//
#include <hip/hip_runtime.h>
#include <stdint.h>

#define T_STEPS 64
#define BATCH   512
#define OBS_DIM 256
#define ACT_DIM 32
#define HID     1024
#define FEAT    512
#define GDIM    3072
#define KIH     288
#define NBLK    256
#define GMEMB   32          // blocks per group
#define LOG2PI  1.8378770664093453f

typedef __attribute__((ext_vector_type(8))) short  short8;   // 8 bf16
typedef __attribute__((ext_vector_type(4))) float  floatx4;  // MFMA C/D frag
typedef unsigned long long ull;

__device__ __forceinline__ float bf2f(unsigned int u) {
    return __uint_as_float(u << 16);
}
__device__ __forceinline__ unsigned int f2bf(float f) {
    unsigned int u = __float_as_uint(f);
    return (u + 0x7FFFu + ((u >> 16) & 1u)) >> 16;  // RNE
}
__device__ __forceinline__ float elu1(float x)  { return x > 0.f ? x : expm1f(x); }
__device__ __forceinline__ float sigm(float x)  { return 1.f / (1.f + expf(-x)); }

// Device-coherent accessors (compile to plain global ops with sc0/sc1 bypass;
// compiler tracks vmcnt correctly — no inline asm).
__device__ __forceinline__ unsigned int dev_ld(const unsigned int* p) {
    return __hip_atomic_load(p, __ATOMIC_RELAXED, __HIP_MEMORY_SCOPE_AGENT);
}
__device__ __forceinline__ ull dev_ld64(const ull* p) {
    return __hip_atomic_load(p, __ATOMIC_RELAXED, __HIP_MEMORY_SCOPE_AGENT);
}
__device__ __forceinline__ void dev_st(unsigned int* p, unsigned int v) {
    __hip_atomic_store(p, v, __ATOMIC_RELAXED, __HIP_MEMORY_SCOPE_AGENT);
}
__device__ __forceinline__ float dev_ldf(const float* p) {
    return __uint_as_float(dev_ld((const unsigned int*)p));
}
__device__ __forceinline__ void dev_stf(float* p, float v) {
    dev_st((unsigned int*)p, __float_as_uint(v));
}

struct Params {
    const float* obs; const float* action; const float* reward;
    const float* b_ih; const float* b_hh;
    const float* b1o; const float* b1r; const float* b2o; const float* b2r;
    const unsigned short* Ws1; const unsigned short* Wih;
    const unsigned short* W1o; const unsigned short* W1r;
    const unsigned short* W2o; const unsigned short* w2r;
    const float* bias_s1;
    unsigned short* Z1; unsigned short* Z2; unsigned short* Xbuf; unsigned short* hbf;
    float* GH; float* h; float* accum; float* out;
    int* bar;
};

// ---------------------------------------------------------------------------
// Group barrier (R5, proven): monotonic epoch, relaxed agent atomics.
// __syncthreads drains vmcnt -> coherent stores are at the MALL before arrive.
// ---------------------------------------------------------------------------
__device__ __forceinline__ void gbar(int* cnt, int* gen, int& epoch, int members) {
    __syncthreads();
    if (threadIdx.x == 0) {
        __builtin_amdgcn_fence(__ATOMIC_RELEASE, "workgroup");
        epoch++;
        int prev = __hip_atomic_fetch_add(cnt, 1, __ATOMIC_RELAXED,
                                          __HIP_MEMORY_SCOPE_AGENT);
        if (prev == members * epoch - 1) {
            __hip_atomic_store(gen, epoch, __ATOMIC_RELAXED,
                               __HIP_MEMORY_SCOPE_AGENT);
        } else {
            while (__hip_atomic_load(gen, __ATOMIC_RELAXED,
                                     __HIP_MEMORY_SCOPE_AGENT) < epoch)
                __builtin_amdgcn_s_sleep(8);
        }
        __builtin_amdgcn_fence(__ATOMIC_ACQUIRE, "workgroup");
    }
    __syncthreads();
}

// ---------------------------------------------------------------------------
// S1: C[64 x 4096] = hbf[g] @ Ws1^T + bias. member tile 64 x 128, K=1024.
// A staged in 128-K chunks (8 u64/thread), pipelined 1 chunk ahead.
// B (weights) plain-cached reg-prefetch per 64-K. LDS: A 64x136, B 128x72.
// ---------------------------------------------------------------------------
__device__ __forceinline__ void s1_stage(const Params& p, unsigned short* lds,
                                         int g, int m) {
    const int tid = threadIdx.x, lane = tid & 63, wv = tid >> 6;
    const int wr = wv & 1, wc = wv >> 1, fr = lane & 15, fq = lane >> 4;
    const int rowg = g * 64, col0 = m * 128;
    unsigned short* ldsA = lds;               // 64 x 136 shorts (one 128k chunk)
    unsigned short* ldsB = lds + 64 * 136;    // 128 x 72 shorts

    floatx4 acc[2][4];
    floatx4 z4 = {0.f, 0.f, 0.f, 0.f};
#pragma unroll
    for (int mi = 0; mi < 2; ++mi)
#pragma unroll
        for (int n = 0; n < 4; ++n) acc[mi][n] = z4;

    const ull* Aq = (const ull*)(p.hbf + (size_t)rowg * HID);   // row stride 256 u64
    const unsigned short* Bg = p.Ws1 + (size_t)col0 * HID;

    ull apf[8];
#pragma unroll
    for (int j = 0; j < 8; ++j) { int f = tid + 256 * j;
        apf[j] = dev_ld64(Aq + (size_t)(f >> 5) * 256 + (f & 31)); }
    uint4 rb[4];
#pragma unroll
    for (int i = 0; i < 4; ++i) { int c = tid + 256 * i;
        rb[i] = *(const uint4*)(Bg + (size_t)(c >> 3) * HID + ((c & 7) << 3)); }

    for (int it = 0; it < 16; ++it) {
        __syncthreads();
        if ((it & 1) == 0) {
#pragma unroll
            for (int j = 0; j < 8; ++j) { int f = tid + 256 * j;
                *(ull*)(ldsA + (size_t)(f >> 5) * 136 + ((f & 31) << 2)) = apf[j]; }
        }
#pragma unroll
        for (int i = 0; i < 4; ++i) { int c = tid + 256 * i;
            *(uint4*)(ldsB + (c >> 3) * 72 + ((c & 7) << 3)) = rb[i]; }
        __syncthreads();
        if ((it & 1) == 0 && it < 14) {
            int c2 = (it >> 1) + 1;
#pragma unroll
            for (int j = 0; j < 8; ++j) { int f = tid + 256 * j;
                apf[j] = dev_ld64(Aq + (size_t)(f >> 5) * 256 + c2 * 32 + (f & 31)); }
        }
        if (it < 15) {
            int k0n = (it + 1) * 64;
#pragma unroll
            for (int i = 0; i < 4; ++i) { int c = tid + 256 * i;
                rb[i] = *(const uint4*)(Bg + (size_t)(c >> 3) * HID + k0n + ((c & 7) << 3)); }
        }
        const int asub = (it & 1) * 64;
#pragma unroll
        for (int ks = 0; ks < 2; ++ks) {
            short8 af[2], bf8[4];
#pragma unroll
            for (int mi = 0; mi < 2; ++mi)
                af[mi] = *(const short8*)(ldsA + (wr * 32 + mi * 16 + fr) * 136 + asub + ks * 32 + fq * 8);
#pragma unroll
            for (int n = 0; n < 4; ++n)
                bf8[n] = *(const short8*)(ldsB + (wc * 64 + n * 16 + fr) * 72 + ks * 32 + fq * 8);
#pragma unroll
            for (int mi = 0; mi < 2; ++mi)
#pragma unroll
                for (int n = 0; n < 4; ++n)
                    acc[mi][n] = __builtin_amdgcn_mfma_f32_16x16x32_bf16(
                        af[mi], bf8[n], acc[mi][n], 0, 0, 0);
        }
    }
    const bool isZ1 = (col0 < 1024);
#pragma unroll
    for (int mi = 0; mi < 2; ++mi)
#pragma unroll
        for (int n = 0; n < 4; ++n)
#pragma unroll
            for (int j = 0; j < 4; ++j) {
                int row = rowg + wr * 32 + mi * 16 + fq * 4 + j;
                int col = col0 + wc * 64 + n * 16 + fr;
                float v = acc[mi][n][j] + p.bias_s1[col];
                if (isZ1) {
                    unsigned int ow = f2bf(elu1(v));
                    unsigned int pr = __shfl_xor(ow, 1, 64);
                    if (!(fr & 1))
                        dev_st((unsigned int*)(p.Z1 + row * HID + col), ow | (pr << 16));
                } else {
                    dev_stf(p.GH + (size_t)row * GDIM + (col - 1024), v);
                }
            }
}

// ---------------------------------------------------------------------------
// S2: Z2 = elu(Z1 half @ W1z^T + b). member: z=m>>4, col0=(m&15)*32.
// tile 64x32, K=512, A chunks of 128k pipelined. LDS: A 64x136, B 32x72.
// ---------------------------------------------------------------------------
__device__ __forceinline__ void s2_stage(const Params& p, unsigned short* lds,
                                         int g, int m) {
    const int tid = threadIdx.x, lane = tid & 63, wv = tid >> 6;
    const int wr = wv & 1, wc = wv >> 1, fr = lane & 15, fq = lane >> 4;
    const int rowg = g * 64;
    const int z = m >> 4, col0 = (m & 15) * 32;
    unsigned short* ldsA = lds;               // 64 x 136
    unsigned short* ldsB = lds + 64 * 136;    // 32 x 72

    floatx4 acc[2];
    floatx4 z4 = {0.f, 0.f, 0.f, 0.f};
    acc[0] = z4; acc[1] = z4;

    const ull* Aq = (const ull*)(p.Z1 + (size_t)rowg * HID + z * FEAT);
    const unsigned short* Bg = (z ? p.W1r : p.W1o) + (size_t)col0 * FEAT;
    const float* bias = z ? p.b1r : p.b1o;

    ull apf[8];
#pragma unroll
    for (int j = 0; j < 8; ++j) { int f = tid + 256 * j;
        apf[j] = dev_ld64(Aq + (size_t)(f >> 5) * 256 + (f & 31)); }
    uint4 rb = *(const uint4*)(Bg + (size_t)(tid >> 3) * FEAT + ((tid & 7) << 3));

    for (int it = 0; it < 8; ++it) {
        __syncthreads();
        if ((it & 1) == 0) {
#pragma unroll
            for (int j = 0; j < 8; ++j) { int f = tid + 256 * j;
                *(ull*)(ldsA + (size_t)(f >> 5) * 136 + ((f & 31) << 2)) = apf[j]; }
        }
        *(uint4*)(ldsB + (tid >> 3) * 72 + ((tid & 7) << 3)) = rb;
        __syncthreads();
        if ((it & 1) == 0 && it < 6) {
            int c2 = (it >> 1) + 1;
#pragma unroll
            for (int j = 0; j < 8; ++j) { int f = tid + 256 * j;
                apf[j] = dev_ld64(Aq + (size_t)(f >> 5) * 256 + c2 * 32 + (f & 31)); }
        }
        if (it < 7) {
            int k0n = (it + 1) * 64;
            rb = *(const uint4*)(Bg + (size_t)(tid >> 3) * FEAT + k0n + ((tid & 7) << 3));
        }
        const int asub = (it & 1) * 64;
#pragma unroll
        for (int ks = 0; ks < 2; ++ks) {
            short8 bf8 = *(const short8*)(ldsB + (wc * 16 + fr) * 72 + ks * 32 + fq * 8);
#pragma unroll
            for (int mi = 0; mi < 2; ++mi) {
                short8 af = *(const short8*)(ldsA + (wr * 32 + mi * 16 + fr) * 136 + asub + ks * 32 + fq * 8);
                acc[mi] = __builtin_amdgcn_mfma_f32_16x16x32_bf16(af, bf8, acc[mi], 0, 0, 0);
            }
        }
    }
#pragma unroll
    for (int mi = 0; mi < 2; ++mi)
#pragma unroll
        for (int j = 0; j < 4; ++j) {
            int row = rowg + wr * 32 + mi * 16 + fq * 4 + j;
            int col = col0 + wc * 16 + fr;
            float v = acc[mi][j] + bias[col];
            unsigned int ow = f2bf(elu1(v));
            unsigned int pr = __shfl_xor(ow, 1, 64);
            if (!(fr & 1))
                dev_st((unsigned int*)(p.Z2 + row * HID + z * FEAT + col), ow | (pr << 16));
        }
}

// ---------------------------------------------------------------------------
// S3: m<8: obs head tile 64x32, K=512 (same pipeline as S2) -> out/Xbuf/loss.
//     m==8: act copy. m in 16..31: reward head, 4 rows (1 per wave).
// ---------------------------------------------------------------------------
__device__ __forceinline__ void s3_stage(const Params& p, unsigned short* lds,
                                         int g, int m, int t) {
    const int tid = threadIdx.x, lane = tid & 63, wv = tid >> 6;
    const int wr = wv & 1, wc = wv >> 1, fr = lane & 15, fq = lane >> 4;
    const int rowg = g * 64;

    if (m < 8) {
        const int col0 = m * 32;
        unsigned short* ldsA = lds;               // 64 x 136
        unsigned short* ldsB = lds + 64 * 136;    // 32 x 72
        floatx4 acc[2];
        floatx4 z4 = {0.f, 0.f, 0.f, 0.f};
        acc[0] = z4; acc[1] = z4;

        const ull* Aq = (const ull*)(p.Z2 + (size_t)rowg * HID);   // obs half
        const unsigned short* Bg = p.W2o + (size_t)col0 * FEAT;

        ull apf[8];
#pragma unroll
        for (int j = 0; j < 8; ++j) { int f = tid + 256 * j;
            apf[j] = dev_ld64(Aq + (size_t)(f >> 5) * 256 + (f & 31)); }
        uint4 rb = *(const uint4*)(Bg + (size_t)(tid >> 3) * FEAT + ((tid & 7) << 3));

        for (int it = 0; it < 8; ++it) {
            __syncthreads();
            if ((it & 1) == 0) {
#pragma unroll
                for (int j = 0; j < 8; ++j) { int f = tid + 256 * j;
                    *(ull*)(ldsA + (size_t)(f >> 5) * 136 + ((f & 31) << 2)) = apf[j]; }
            }
            *(uint4*)(ldsB + (tid >> 3) * 72 + ((tid & 7) << 3)) = rb;
            __syncthreads();
            if ((it & 1) == 0 && it < 6) {
                int c2 = (it >> 1) + 1;
#pragma unroll
                for (int j = 0; j < 8; ++j) { int f = tid + 256 * j;
                    apf[j] = dev_ld64(Aq + (size_t)(f >> 5) * 256 + c2 * 32 + (f & 31)); }
            }
            if (it < 7) {
                int k0n = (it + 1) * 64;
                rb = *(const uint4*)(Bg + (size_t)(tid >> 3) * FEAT + k0n + ((tid & 7) << 3));
            }
            const int asub = (it & 1) * 64;
#pragma unroll
            for (int ks = 0; ks < 2; ++ks) {
                short8 bf8 = *(const short8*)(ldsB + (wc * 16 + fr) * 72 + ks * 32 + fq * 8);
#pragma unroll
                for (int mi = 0; mi < 2; ++mi) {
                    short8 af = *(const short8*)(ldsA + (wr * 32 + mi * 16 + fr) * 136 + asub + ks * 32 + fq * 8);
                    acc[mi] = __builtin_amdgcn_mfma_f32_16x16x32_bf16(af, bf8, acc[mi], 0, 0, 0);
                }
            }
        }
        const int col = col0 + wc * 16 + fr;
        const float b2oc = p.b2o[col];
        float lsum = 0.f;
#pragma unroll
        for (int mi = 0; mi < 2; ++mi)
#pragma unroll
            for (int j = 0; j < 4; ++j) {
                int row = rowg + wr * 32 + mi * 16 + fq * 4 + j;
                float mval = acc[mi][j] + b2oc;
                size_t oidx = (size_t)t * BATCH * OBS_DIM + (size_t)row * OBS_DIM + col;
                p.out[1 + oidx] = mval;
                unsigned int ow = f2bf(mval);
                unsigned int pr = __shfl_xor(ow, 1, 64);
                if (!(fr & 1))
                    dev_st((unsigned int*)(p.Xbuf + row * KIH + col), ow | (pr << 16));
                float d = p.obs[oidx] - mval;
                lsum += d * d;
            }
#pragma unroll
        for (int off = 32; off > 0; off >>= 1) lsum += __shfl_down(lsum, off, 64);
        if (lane == 0) atomicAdd(p.accum + 0, lsum);
    } else if (m == 8) {
        for (int e = tid; e < 64 * 16; e += 256) {
            int row = rowg + (e >> 4), cp = (e & 15) * 2;
            const float* ap = p.action + ((size_t)t * BATCH + row) * ACT_DIM + cp;
            unsigned int lo = f2bf(ap[0]);
            unsigned int hi = f2bf(ap[1]);
            dev_st((unsigned int*)(p.Xbuf + row * KIH + OBS_DIM + cp), lo | (hi << 16));
        }
    } else if (m >= 16) {
        // reward head: member handles 4 rows, one per wave
        const int row = rowg + (m - 16) * 4 + wv;
        const ull* zq = (const ull*)(p.Z2 + (size_t)row * HID + FEAT) + lane * 2;
        ull z0 = dev_ld64(zq);
        ull z1 = dev_ld64(zq + 1);
        short8 w8 = *(const short8*)(p.w2r + lane * 8);
        float s = 0.f;
#pragma unroll
        for (int k = 0; k < 4; ++k) {
            unsigned int u = (unsigned int)(z0 >> (16 * k)) & 0xFFFFu;
            s += bf2f(u) * bf2f((unsigned int)(unsigned short)w8[k]);
        }
#pragma unroll
        for (int k = 0; k < 4; ++k) {
            unsigned int u = (unsigned int)(z1 >> (16 * k)) & 0xFFFFu;
            s += bf2f(u) * bf2f((unsigned int)(unsigned short)w8[4 + k]);
        }
#pragma unroll
        for (int off = 32; off > 0; off >>= 1) s += __shfl_down(s, off, 64);
        if (lane == 0) {
            float mm = s + p.b2r[0];
            p.out[1 + (size_t)T_STEPS * BATCH * OBS_DIM + (size_t)t * BATCH + row] = mm;
            float d = p.reward[(size_t)t * BATCH + row] - mm;
            atomicAdd(p.accum + 1, d * d);
        }
    }
}

// ---------------------------------------------------------------------------
// S4: gi = Xbuf[g rows] @ Wih^T (3 gates) -> GRU -> h, hbf.
// member: col0 = m*32. K=288, 3 chunks of 96k, A pipelined (6 u64/thread).
// LDS: A 64x104, B 96x104.
// ---------------------------------------------------------------------------
__device__ __forceinline__ void s4_stage(const Params& p, unsigned short* lds,
                                         int g, int m, int use_gh) {
    const int tid = threadIdx.x, lane = tid & 63, wv = tid >> 6;
    const int wr = wv & 1, wc = wv >> 1, fr = lane & 15, fq = lane >> 4;
    const int rowg = g * 64;
    const int col0 = m * 32;
    unsigned short* ldsA = lds;               // 64 x 104
    unsigned short* ldsB = lds + 64 * 104;    // 96 x 104

    floatx4 acc[3][2];
    floatx4 z4 = {0.f, 0.f, 0.f, 0.f};
#pragma unroll
    for (int g3 = 0; g3 < 3; ++g3) { acc[g3][0] = z4; acc[g3][1] = z4; }

    const ull* Xq = (const ull*)(p.Xbuf + (size_t)rowg * KIH);   // row stride 72 u64
    ull apf[6];
#pragma unroll
    for (int j = 0; j < 6; ++j) { int f = tid + 256 * j;
        apf[j] = dev_ld64(Xq + (size_t)(f / 24) * 72 + (f % 24)); }

    for (int c = 0; c < 3; ++c) {
        __syncthreads();
#pragma unroll
        for (int j = 0; j < 6; ++j) { int f = tid + 256 * j;
            *(ull*)(ldsA + (size_t)(f / 24) * 104 + ((f % 24) << 2)) = apf[j]; }
        // B: plain-cached direct staging (compiler-managed waits)
        const int k0 = c * 96;
        for (int cc = tid; cc < 1152; cc += 256) {
            int r = cc / 12, ko = (cc - r * 12) * 8;
            int g3 = r >> 5, cr = r & 31;
            *(uint4*)(ldsB + r * 104 + ko) =
                *(const uint4*)(p.Wih + (size_t)(g3 * HID + col0 + cr) * KIH + k0 + ko);
        }
        __syncthreads();
        if (c < 2) {
#pragma unroll
            for (int j = 0; j < 6; ++j) { int f = tid + 256 * j;
                apf[j] = dev_ld64(Xq + (size_t)(f / 24) * 72 + (c + 1) * 24 + (f % 24)); }
        }
#pragma unroll
        for (int ks = 0; ks < 3; ++ks) {
            short8 af[2];
#pragma unroll
            for (int mi = 0; mi < 2; ++mi)
                af[mi] = *(const short8*)(ldsA + (wr * 32 + mi * 16 + fr) * 104 + ks * 32 + fq * 8);
#pragma unroll
            for (int g3 = 0; g3 < 3; ++g3) {
                short8 bf8 = *(const short8*)(ldsB + (g3 * 32 + wc * 16 + fr) * 104 + ks * 32 + fq * 8);
#pragma unroll
                for (int mi = 0; mi < 2; ++mi)
                    acc[g3][mi] = __builtin_amdgcn_mfma_f32_16x16x32_bf16(
                        af[mi], bf8, acc[g3][mi], 0, 0, 0);
            }
        }
    }

    const int col = col0 + wc * 16 + fr;
    const float bir = p.b_ih[col];
    const float biz = p.b_ih[HID + col];
    const float bin = p.b_ih[2 * HID + col];
    float hrv[2][4], hzv[2][4], hnv[2][4], hpv[2][4];
    if (use_gh) {
#pragma unroll
        for (int mi = 0; mi < 2; ++mi)
#pragma unroll
            for (int j = 0; j < 4; ++j) {
                int row = rowg + wr * 32 + mi * 16 + fq * 4 + j;
                const float* gh = p.GH + (size_t)row * GDIM + col;
                hrv[mi][j] = dev_ldf(gh);
                hzv[mi][j] = dev_ldf(gh + HID);
                hnv[mi][j] = dev_ldf(gh + 2 * HID);
                hpv[mi][j] = dev_ldf(p.h + (size_t)row * HID + col);
            }
    } else {
        float br = p.b_hh[col], bz = p.b_hh[HID + col], bn = p.b_hh[2 * HID + col];
#pragma unroll
        for (int mi = 0; mi < 2; ++mi)
#pragma unroll
            for (int j = 0; j < 4; ++j) {
                hrv[mi][j] = br; hzv[mi][j] = bz; hnv[mi][j] = bn; hpv[mi][j] = 0.f;
            }
    }
#pragma unroll
    for (int mi = 0; mi < 2; ++mi)
#pragma unroll
        for (int j = 0; j < 4; ++j) {
            int row = rowg + wr * 32 + mi * 16 + fq * 4 + j;
            float r  = sigm(acc[0][mi][j] + bir + hrv[mi][j]);
            float z  = sigm(acc[1][mi][j] + biz + hzv[mi][j]);
            float nn = tanhf(acc[2][mi][j] + bin + r * hnv[mi][j]);
            float hv = (1.f - z) * nn + z * hpv[mi][j];
            dev_stf(p.h + (size_t)row * HID + col, hv);
            unsigned int ow = f2bf(hv);
            unsigned int pr = __shfl_xor(ow, 1, 64);
            if (!(fr & 1))
                dev_st((unsigned int*)(p.hbf + row * HID + col), ow | (pr << 16));
        }
}

// ---------------------------------------------------------------------------
// Persistent rollout: 8 groups x 32 blocks (64 batch rows each).
// ---------------------------------------------------------------------------
__global__ __launch_bounds__(256, 1) void k_persist(Params p) {
    __shared__ unsigned short lds[17920];   // max: S1 = 64*136 + 128*72

    const int bid = blockIdx.x;
    const int g = bid & 7;       // group (== XCD under round-robin heuristic)
    const int m = bid >> 3;      // member 0..31
    int* gcnt = p.bar + g * 128;
    int* ggen = p.bar + g * 128 + 64;
    int epoch = 0;

    s4_stage(p, lds, g, m, 0);
    gbar(gcnt, ggen, epoch, GMEMB);

    for (int t = 0; t < T_STEPS; ++t) {
        s1_stage(p, lds, g, m);
        gbar(gcnt, ggen, epoch, GMEMB);
        s2_stage(p, lds, g, m);
        gbar(gcnt, ggen, epoch, GMEMB);
        s3_stage(p, lds, g, m, t);
        gbar(gcnt, ggen, epoch, GMEMB);
        if (t < T_STEPS - 1) {
            s4_stage(p, lds, g, m, 1);
            gbar(gcnt, ggen, epoch, GMEMB);
        }
    }

    int* rcnt = p.bar + 8 * 128;
    int* rgen = p.bar + 8 * 128 + 64;
    int repoch = 0;
    gbar(rcnt, rgen, repoch, NBLK);

    if (bid == 0 && threadIdx.x == 0) {
        const float inv = 1.f / (float)(T_STEPS * BATCH);
        float a0 = dev_ldf(p.accum + 0);
        float a1 = dev_ldf(p.accum + 1);
        p.out[0] = 0.5f * a0 * inv + 128.f * LOG2PI
                 + 0.5f * a1 * inv + 0.5f * LOG2PI;
    }
}

// ---------------------------------------------------------------------------
__global__ void k_convert(
    const float* __restrict__ ow0, const float* __restrict__ rw0,
    const float* __restrict__ whh, const float* __restrict__ wih,
    const float* __restrict__ ow1, const float* __restrict__ rw1,
    const float* __restrict__ ow2, const float* __restrict__ rw2,
    const float* __restrict__ ob0, const float* __restrict__ rb0,
    const float* __restrict__ bhh,
    unsigned short* __restrict__ Ws1, unsigned short* __restrict__ Wih,
    unsigned short* __restrict__ W1o, unsigned short* __restrict__ W1r,
    unsigned short* __restrict__ W2o, unsigned short* __restrict__ w2r,
    float* __restrict__ bias_s1)
{
    const int i0 = blockIdx.x * 256 + threadIdx.x;
    const int stride = gridDim.x * 256;
    for (int i = i0; i < 4096 * 1024; i += stride) {
        int row = i >> 10;
        float v = (row < 512) ? ow0[i]
                : (row < 1024) ? rw0[i - 512 * 1024]
                               : whh[i - 1024 * 1024];
        Ws1[i] = (unsigned short)f2bf(v);
    }
    for (int i = i0; i < GDIM * KIH; i += stride) Wih[i] = (unsigned short)f2bf(wih[i]);
    for (int i = i0; i < FEAT * FEAT; i += stride) {
        W1o[i] = (unsigned short)f2bf(ow1[i]);
        W1r[i] = (unsigned short)f2bf(rw1[i]);
    }
    for (int i = i0; i < OBS_DIM * FEAT; i += stride) W2o[i] = (unsigned short)f2bf(ow2[i]);
    for (int i = i0; i < FEAT; i += stride) w2r[i] = (unsigned short)f2bf(rw2[i]);
    for (int i = i0; i < 4096; i += stride)
        bias_s1[i] = (i < 512) ? ob0[i] : (i < 1024) ? rb0[i - 512] : bhh[i - 1024];
}

__global__ void k_init(const float* __restrict__ obs,
                       unsigned short* __restrict__ Xbuf,
                       float* __restrict__ accum,
                       int* __restrict__ bar)
{
    int i = blockIdx.x * 256 + threadIdx.x;
    if (i < BATCH * KIH) {
        int row = i / KIH, col = i - row * KIH;
        Xbuf[i] = (col < OBS_DIM) ? (unsigned short)f2bf(obs[row * OBS_DIM + col])
                                  : (unsigned short)0;
    }
    if (i < 2)    accum[i] = 0.f;
    if (i < 1152) bar[i] = 0;
}

// ---------------------------------------------------------------------------
extern "C" void kernel_launch(void* const* d_in, const int* in_sizes, int n_in,
                              void* d_out, int out_size, void* d_ws, size_t ws_size,
                              hipStream_t stream)
{
    const float* obs      = (const float*)d_in[0];
    const float* action   = (const float*)d_in[1];
    const float* reward   = (const float*)d_in[2];
    const float* gru_w_ih = (const float*)d_in[3];
    const float* gru_w_hh = (const float*)d_in[4];
    const float* gru_b_ih = (const float*)d_in[5];
    const float* gru_b_hh = (const float*)d_in[6];
    const float* obs_w0   = (const float*)d_in[7];
    const float* obs_b0   = (const float*)d_in[8];
    const float* obs_w1   = (const float*)d_in[9];
    const float* obs_b1   = (const float*)d_in[10];
    const float* obs_w2   = (const float*)d_in[11];
    const float* obs_b2   = (const float*)d_in[12];
    const float* rew_w0   = (const float*)d_in[13];
    const float* rew_b0   = (const float*)d_in[14];
    const float* rew_w1   = (const float*)d_in[15];
    const float* rew_b1   = (const float*)d_in[16];
    const float* rew_w2   = (const float*)d_in[17];
    const float* rew_b2   = (const float*)d_in[18];

    char* ws = (char*)d_ws;
    auto alloc = [&](size_t bytes) -> char* {
        char* pr = ws;
        ws += (bytes + 255) & ~(size_t)255;
        return pr;
    };
    unsigned short* Ws1     = (unsigned short*)alloc((size_t)4096 * 1024 * 2);
    unsigned short* Wih     = (unsigned short*)alloc((size_t)GDIM * KIH * 2);
    unsigned short* W1o     = (unsigned short*)alloc((size_t)FEAT * FEAT * 2);
    unsigned short* W1r     = (unsigned short*)alloc((size_t)FEAT * FEAT * 2);
    unsigned short* W2o     = (unsigned short*)alloc((size_t)OBS_DIM * FEAT * 2);
    unsigned short* w2r     = (unsigned short*)alloc((size_t)FEAT * 2);
    float*          bias_s1 = (float*)alloc((size_t)4096 * 4);
    unsigned short* Z1      = (unsigned short*)alloc((size_t)BATCH * HID * 2);
    unsigned short* Z2      = (unsigned short*)alloc((size_t)BATCH * HID * 2);
    float*          GH      = (float*)alloc((size_t)BATCH * GDIM * 4);
    unsigned short* Xbuf    = (unsigned short*)alloc((size_t)BATCH * KIH * 2);
    float*          h       = (float*)alloc((size_t)BATCH * HID * 4);
    unsigned short* hbf     = (unsigned short*)alloc((size_t)BATCH * HID * 2);
    float*          accum   = (float*)alloc(256);
    int*            bar     = (int*)alloc(8192);

    dim3 blk(256);

    k_convert<<<dim3(1024), blk, 0, stream>>>(
        obs_w0, rew_w0, gru_w_hh, gru_w_ih, obs_w1, rew_w1, obs_w2, rew_w2,
        obs_b0, rew_b0, gru_b_hh, Ws1, Wih, W1o, W1r, W2o, w2r, bias_s1);

    k_init<<<dim3((BATCH * KIH + 255) / 256), blk, 0, stream>>>(obs, Xbuf, accum, bar);

    Params hp;
    hp.obs = obs; hp.action = action; hp.reward = reward;
    hp.b_ih = gru_b_ih; hp.b_hh = gru_b_hh;
    hp.b1o = obs_b1; hp.b1r = rew_b1; hp.b2o = obs_b2; hp.b2r = rew_b2;
    hp.Ws1 = Ws1; hp.Wih = Wih; hp.W1o = W1o; hp.W1r = W1r;
    hp.W2o = W2o; hp.w2r = w2r; hp.bias_s1 = bias_s1;
    hp.Z1 = Z1; hp.Z2 = Z2; hp.Xbuf = Xbuf; hp.hbf = hbf;
    hp.GH = GH; hp.h = h; hp.accum = accum; hp.out = (float*)d_out;
    hp.bar = bar;

    k_persist<<<dim3(NBLK), blk, 0, stream>>>(hp);
}